// Round 1
// baseline (9646.828 us; speedup 1.0000x reference)
//
#include <hip/hip_runtime.h>

static constexpr int NN = 100000;   // nodes
static constexpr int NE = 1600000;  // edges
static constexpr int NB = 256;     // graphs
static constexpr int NO = 32;      // orders per graph
static constexpr int HD = 128;     // hidden dim
static constexpr long NH = (long)NN * HD;

// ---------------- scatter-add: agg[dst] += h[src] ----------------
__global__ void scatter_kernel(const float* __restrict__ h, const int* __restrict__ ei,
                               float* __restrict__ agg) {
  int idx = blockIdx.x * blockDim.x + threadIdx.x;
  if (idx >= NE * 32) return;            // 4 floats per thread
  int e  = idx >> 5;
  int c4 = (idx & 31) << 2;
  int s = ei[e];
  int d = ei[NE + e];
  const float4 v = *reinterpret_cast<const float4*>(h + (long)s * HD + c4);
  float* p = agg + (long)d * HD + c4;
  unsafeAtomicAdd(p + 0, v.x);
  unsafeAtomicAdd(p + 1, v.y);
  unsafeAtomicAdd(p + 2, v.z);
  unsafeAtomicAdd(p + 3, v.w);
}

// ---------------- fused (A [+ Hadd]) @ W + b, optional ReLU ----------------
// A: [NN,128], W: [128,128] row-major, out: [NN,128]
// block: 256 threads, 16 rows; thread computes 8 outputs of one row.
template <bool RELU_OUT, bool ADD_H>
__global__ void mlp_gemm(const float* __restrict__ A, const float* __restrict__ Hadd,
                         const float* __restrict__ W, const float* __restrict__ bias,
                         float* __restrict__ out) {
  __shared__ float As[16][128];
  const int row0 = blockIdx.x * 16;
  const int tid = threadIdx.x;
  for (int i = tid; i < 16 * 128; i += 256) {
    int r = i >> 7, c = i & 127;
    float v = A[(long)(row0 + r) * HD + c];
    if (ADD_H) v += Hadd[(long)(row0 + r) * HD + c];
    As[r][c] = v;
  }
  __syncthreads();
  const int r  = tid >> 4;
  const int jg = (tid & 15) << 3;
  float acc[8];
#pragma unroll
  for (int j = 0; j < 8; ++j) acc[j] = bias[jg + j];
  for (int k = 0; k < 128; ++k) {
    float a = As[r][k];
    const float4 w0 = *reinterpret_cast<const float4*>(W + k * 128 + jg);
    const float4 w1 = *reinterpret_cast<const float4*>(W + k * 128 + jg + 4);
    acc[0] += a * w0.x; acc[1] += a * w0.y; acc[2] += a * w0.z; acc[3] += a * w0.w;
    acc[4] += a * w1.x; acc[5] += a * w1.y; acc[6] += a * w1.z; acc[7] += a * w1.w;
  }
  float* o = out + (long)(row0 + r) * HD + jg;
#pragma unroll
  for (int j = 0; j < 8; ++j) {
    float v = acc[j];
    if (RELU_OUT) v = fmaxf(v, 0.0f);
    o[j] = v;
  }
}

// ---------------- batchnorm stats: column sums / sumsq ----------------
__global__ void bn_stats(const float* __restrict__ z, float* __restrict__ accum) {
  const int c = threadIdx.x;  // 128
  float s = 0.0f, q = 0.0f;
  for (int row = blockIdx.x; row < NN; row += gridDim.x) {
    float v = z[(long)row * HD + c];
    s += v;
    q += v * v;
  }
  atomicAdd(&accum[c], s);
  atomicAdd(&accum[128 + c], q);
}

__global__ void bn_finalize(const float* __restrict__ accum, const float* __restrict__ gamma,
                            const float* __restrict__ beta, float* __restrict__ ss) {
  const int c = threadIdx.x;  // 128
  const float n = (float)NN;
  float mu  = accum[c] / n;
  float var = accum[128 + c] / n - mu * mu;
  float rstd = rsqrtf(var + 1e-5f);
  float sc = rstd * gamma[c];
  ss[c] = sc;
  ss[128 + c] = beta[c] - mu * sc;
}

template <bool RELU>
__global__ void bn_apply(const float* __restrict__ z, const float* __restrict__ ss,
                         float* __restrict__ out) {
  int idx = blockIdx.x * blockDim.x + threadIdx.x;
  if (idx >= NN * 32) return;  // 4 floats per thread
  int c4 = (idx & 31) << 2;
  const float4 v = *reinterpret_cast<const float4*>(z + (long)idx * 4);
  float4 r;
  r.x = v.x * ss[c4 + 0] + ss[128 + c4 + 0];
  r.y = v.y * ss[c4 + 1] + ss[128 + c4 + 1];
  r.z = v.z * ss[c4 + 2] + ss[128 + c4 + 2];
  r.w = v.w * ss[c4 + 3] + ss[128 + c4 + 3];
  if (RELU) {
    r.x = fmaxf(r.x, 0.0f); r.y = fmaxf(r.y, 0.0f);
    r.z = fmaxf(r.z, 0.0f); r.w = fmaxf(r.w, 0.0f);
  }
  *reinterpret_cast<float4*>(out + (long)idx * 4) = r;
}

// ---------------- pooling: batch is sorted -> segment scan per graph ----------------
__global__ void pool_kernel(const float* __restrict__ h, const int* __restrict__ batch,
                            float* __restrict__ smean, float* __restrict__ smax,
                            float* __restrict__ ssum) {
  const int b = blockIdx.x;   // 256
  const int c = threadIdx.x;  // 128
  int lo = 0, hi = NN;
  while (lo < hi) { int mid = (lo + hi) >> 1; if (batch[mid] < b) lo = mid + 1; else hi = mid; }
  const int start = lo;
  hi = NN;
  while (lo < hi) { int mid = (lo + hi) >> 1; if (batch[mid] < b + 1) lo = mid + 1; else hi = mid; }
  const int end = lo;
  float s = 0.0f, m = -INFINITY;
  for (int row = start; row < end; ++row) {
    float v = h[(long)row * HD + c];
    s += v;
    m = fmaxf(m, v);
  }
  const int cnt = end - start;
  ssum[b * HD + c]  = s;
  smean[b * HD + c] = s / fmaxf((float)cnt, 1.0f);
  smax[b * HD + c]  = (cnt > 0) ? m : 0.0f;
}

// ---------------- order encoder + score head, one block per (b,o) ----------------
__global__ void head_kernel(const float* __restrict__ orders,
                            const float* __restrict__ oW1, const float* __restrict__ ob1,
                            const float* __restrict__ oW2, const float* __restrict__ ob2,
                            const float* __restrict__ sW1, const float* __restrict__ sb1,
                            const float* __restrict__ sW2, const float* __restrict__ sb2,
                            const float* __restrict__ sW3, const float* __restrict__ sb3,
                            const float* __restrict__ smean, const float* __restrict__ smax,
                            const float* __restrict__ ssum, float* __restrict__ out) {
  __shared__ float t1[128];
  __shared__ float comb[512];
  __shared__ float s1[128];
  __shared__ float s2[64];
  const int bo = blockIdx.x;       // b*NO + o
  const int b = bo >> 5;
  const int tid = threadIdx.x;     // 128

  // order encoder layer 1: [32] -> [128], ReLU
  {
    float acc = ob1[tid];
    const float* orow = orders + (long)bo * 32;
    for (int k = 0; k < 32; ++k) acc += orow[k] * oW1[k * 128 + tid];
    t1[tid] = fmaxf(acc, 0.0f);
  }
  comb[tid]       = smean[b * HD + tid];
  comb[128 + tid] = smax[b * HD + tid];
  comb[256 + tid] = ssum[b * HD + tid];
  __syncthreads();
  // order encoder layer 2: [128] -> [128]
  {
    float acc = ob2[tid];
    for (int k = 0; k < 128; ++k) acc += t1[k] * oW2[k * 128 + tid];
    comb[384 + tid] = acc;
  }
  __syncthreads();
  // score layer 1: [512] -> [128], ReLU
  {
    float acc = sb1[tid];
    for (int k = 0; k < 512; ++k) acc += comb[k] * sW1[k * 128 + tid];
    s1[tid] = fmaxf(acc, 0.0f);
  }
  __syncthreads();
  // score layer 2: [128] -> [64], ReLU
  if (tid < 64) {
    float acc = sb2[tid];
    for (int k = 0; k < 128; ++k) acc += s1[k] * sW2[k * 64 + tid];
    s2[tid] = fmaxf(acc, 0.0f);
  }
  __syncthreads();
  // score layer 3: [64] -> [1]
  if (tid == 0) {
    float acc = sb3[0];
    for (int k = 0; k < 64; ++k) acc += s2[k] * sW3[k];
    out[bo] = acc;
  }
}

extern "C" void kernel_launch(void* const* d_in, const int* in_sizes, int n_in,
                              void* d_out, int out_size, void* d_ws, size_t ws_size,
                              hipStream_t stream) {
  const float* x      = (const float*)d_in[0];
  const int*   ei     = (const int*)d_in[1];
  const float* orders = (const float*)d_in[2];
  const int*   batch  = (const int*)d_in[3];
  const float* gW1    = (const float*)d_in[4];
  const float* gb1    = (const float*)d_in[5];
  const float* gW2    = (const float*)d_in[6];
  const float* gb2    = (const float*)d_in[7];
  const float* gamma  = (const float*)d_in[8];
  const float* beta   = (const float*)d_in[9];
  const float* oW1    = (const float*)d_in[10];
  const float* ob1    = (const float*)d_in[11];
  const float* oW2    = (const float*)d_in[12];
  const float* ob2    = (const float*)d_in[13];
  const float* sW1    = (const float*)d_in[14];
  const float* sb1    = (const float*)d_in[15];
  const float* sW2    = (const float*)d_in[16];
  const float* sb2    = (const float*)d_in[17];
  const float* sW3    = (const float*)d_in[18];
  const float* sb3    = (const float*)d_in[19];
  float* out = (float*)d_out;

  char* ws = (char*)d_ws;
  float* bufA = (float*)ws;                       // agg / z / out2   [NN,128]
  float* bufC = (float*)(ws + NH * 4);            // hidden / h       [NN,128]
  char* small = ws + 2 * NH * 4;
  float* accum = (float*)small;                   // 256
  float* ssbn  = accum + 256;                     // 256 (scale|shift)
  float* ssum  = ssbn + 256;                      // 256*128
  float* smean = ssum + NB * HD;                  // 256*128
  float* smax  = smean + NB * HD;                 // 256*128

  const float* hcur = x;
  for (int l = 0; l < 3; ++l) {
    hipMemsetAsync(bufA, 0, NH * sizeof(float), stream);
    scatter_kernel<<<(NE * 32 + 255) / 256, 256, 0, stream>>>(hcur, ei, bufA);
    // hidden = ReLU((agg + h) @ W1 + b1)   (in-place-safe: per-block row ownership)
    mlp_gemm<true, true><<<NN / 16, 256, 0, stream>>>(
        bufA, hcur, gW1 + (long)l * 128 * 128, gb1 + l * 128, bufC);
    // out2 = hidden @ W2 + b2
    mlp_gemm<false, false><<<NN / 16, 256, 0, stream>>>(
        bufC, nullptr, gW2 + (long)l * 128 * 128, gb2 + l * 128, bufA);
    hipMemsetAsync(accum, 0, 256 * sizeof(float), stream);
    bn_stats<<<1024, 128, 0, stream>>>(bufA, accum);
    bn_finalize<<<1, 128, 0, stream>>>(accum, gamma + l * 128, beta + l * 128, ssbn);
    if (l < 2)
      bn_apply<true><<<(NN * 32 + 255) / 256, 256, 0, stream>>>(bufA, ssbn, bufC);
    else
      bn_apply<false><<<(NN * 32 + 255) / 256, 256, 0, stream>>>(bufA, ssbn, bufC);
    hcur = bufC;
  }

  pool_kernel<<<NB, 128, 0, stream>>>(bufC, batch, smean, smax, ssum);
  head_kernel<<<NB * NO, 128, 0, stream>>>(orders, oW1, ob1, oW2, ob2,
                                           sW1, sb1, sW2, sb2, sW3, sb3,
                                           smean, smax, ssum, out);
}

// Round 2
// 2703.867 us; speedup vs baseline: 3.5678x; 3.5678x over previous
//
#include <hip/hip_runtime.h>

static constexpr int NN = 100000;   // nodes
static constexpr int NE = 1600000;  // edges
static constexpr int NB = 256;     // graphs
static constexpr int NO = 32;      // orders per graph
static constexpr int HD = 128;     // hidden dim
static constexpr long NH = (long)NN * HD;

// ---------------- CSR build (once per call; edge_index fixed across layers) ----------------
__global__ void hist_kernel(const int* __restrict__ ei, int* __restrict__ rowptr) {
  int e = blockIdx.x * blockDim.x + threadIdx.x;
  if (e >= NE) return;
  atomicAdd(&rowptr[ei[NE + e]], 1);
}

// in-place exclusive scan of rowptr[0..NN), single block of 1024 threads
__global__ void scan_kernel(int* __restrict__ rowptr) {
  __shared__ int part[1024];
  const int t = threadIdx.x;
  const int C = (NN + 1023) / 1024;
  const int lo = t * C, hi = min(lo + C, NN);
  int s = 0;
  for (int i = lo; i < hi; ++i) s += rowptr[i];
  part[t] = s;
  __syncthreads();
  for (int off = 1; off < 1024; off <<= 1) {
    int v = (t >= off) ? part[t - off] : 0;
    __syncthreads();
    part[t] += v;
    __syncthreads();
  }
  int excl = (t == 0) ? 0 : part[t - 1];
  for (int i = lo; i < hi; ++i) {
    int v = rowptr[i];
    rowptr[i] = excl;
    excl += v;
  }
}

// col[pos] = src; after this kernel rowptr[n] == end offset of node n
__global__ void fill_kernel(const int* __restrict__ ei, int* __restrict__ rowptr,
                            int* __restrict__ col) {
  int e = blockIdx.x * blockDim.x + threadIdx.x;
  if (e >= NE) return;
  int s = ei[e];
  int d = ei[NE + e];
  int pos = atomicAdd(&rowptr[d], 1);
  col[pos] = s;
}

// ---------------- gather: z[n] = h[n] + sum_{j in CSR(n)} h[col[j]] ----------------
// 128 threads per node (one column each), 2 nodes per 256-thread block
__global__ void gather_kernel(const float* __restrict__ h, const int* __restrict__ rowptr,
                              const int* __restrict__ col, float* __restrict__ z) {
  const int node = blockIdx.x * 2 + (threadIdx.x >> 7);
  const int c = threadIdx.x & 127;
  const int lo = (node == 0) ? 0 : rowptr[node - 1];
  const int hi = rowptr[node];
  float acc = h[(long)node * HD + c];
  for (int j = lo; j < hi; ++j) {
    int s = col[j];
    acc += h[(long)s * HD + c];
  }
  z[(long)node * HD + c] = acc;
}

// ---------------- fused A @ W + b, optional ReLU ----------------
// A: [NN,128], W: [128,128] row-major, out: [NN,128]
template <bool RELU_OUT>
__global__ void mlp_gemm(const float* __restrict__ A, const float* __restrict__ W,
                         const float* __restrict__ bias, float* __restrict__ out) {
  __shared__ float As[16][128];
  const int row0 = blockIdx.x * 16;
  const int tid = threadIdx.x;
  for (int i = tid; i < 16 * 128; i += 256) {
    int r = i >> 7, c = i & 127;
    As[r][c] = A[(long)(row0 + r) * HD + c];
  }
  __syncthreads();
  const int r  = tid >> 4;
  const int jg = (tid & 15) << 3;
  float acc[8];
#pragma unroll
  for (int j = 0; j < 8; ++j) acc[j] = bias[jg + j];
  for (int k = 0; k < 128; ++k) {
    float a = As[r][k];
    const float4 w0 = *reinterpret_cast<const float4*>(W + k * 128 + jg);
    const float4 w1 = *reinterpret_cast<const float4*>(W + k * 128 + jg + 4);
    acc[0] += a * w0.x; acc[1] += a * w0.y; acc[2] += a * w0.z; acc[3] += a * w0.w;
    acc[4] += a * w1.x; acc[5] += a * w1.y; acc[6] += a * w1.z; acc[7] += a * w1.w;
  }
  float* o = out + (long)(row0 + r) * HD + jg;
#pragma unroll
  for (int j = 0; j < 8; ++j) {
    float v = acc[j];
    if (RELU_OUT) v = fmaxf(v, 0.0f);
    o[j] = v;
  }
}

// ---------------- batchnorm ----------------
__global__ void bn_stats(const float* __restrict__ z, float* __restrict__ accum) {
  const int c = threadIdx.x;  // 128
  float s = 0.0f, q = 0.0f;
  for (int row = blockIdx.x; row < NN; row += gridDim.x) {
    float v = z[(long)row * HD + c];
    s += v;
    q += v * v;
  }
  atomicAdd(&accum[c], s);
  atomicAdd(&accum[128 + c], q);
}

__global__ void bn_finalize(const float* __restrict__ accum, const float* __restrict__ gamma,
                            const float* __restrict__ beta, float* __restrict__ ss) {
  const int c = threadIdx.x;  // 128
  const float n = (float)NN;
  float mu  = accum[c] / n;
  float var = accum[128 + c] / n - mu * mu;
  float rstd = rsqrtf(var + 1e-5f);
  float sc = rstd * gamma[c];
  ss[c] = sc;
  ss[128 + c] = beta[c] - mu * sc;
}

template <bool RELU>
__global__ void bn_apply(const float* __restrict__ z, const float* __restrict__ ss,
                         float* __restrict__ out) {
  int idx = blockIdx.x * blockDim.x + threadIdx.x;
  if (idx >= NN * 32) return;  // 4 floats per thread
  int c4 = (idx & 31) << 2;
  const float4 v = *reinterpret_cast<const float4*>(z + (long)idx * 4);
  float4 r;
  r.x = v.x * ss[c4 + 0] + ss[128 + c4 + 0];
  r.y = v.y * ss[c4 + 1] + ss[128 + c4 + 1];
  r.z = v.z * ss[c4 + 2] + ss[128 + c4 + 2];
  r.w = v.w * ss[c4 + 3] + ss[128 + c4 + 3];
  if (RELU) {
    r.x = fmaxf(r.x, 0.0f); r.y = fmaxf(r.y, 0.0f);
    r.z = fmaxf(r.z, 0.0f); r.w = fmaxf(r.w, 0.0f);
  }
  *reinterpret_cast<float4*>(out + (long)idx * 4) = r;
}

// ---------------- pooling: batch is sorted -> segment scan per graph ----------------
__global__ void pool_kernel(const float* __restrict__ h, const int* __restrict__ batch,
                            float* __restrict__ smean, float* __restrict__ smax,
                            float* __restrict__ ssum) {
  const int b = blockIdx.x;   // 256
  const int c = threadIdx.x;  // 128
  int lo = 0, hi = NN;
  while (lo < hi) { int mid = (lo + hi) >> 1; if (batch[mid] < b) lo = mid + 1; else hi = mid; }
  const int start = lo;
  hi = NN;
  while (lo < hi) { int mid = (lo + hi) >> 1; if (batch[mid] < b + 1) lo = mid + 1; else hi = mid; }
  const int end = lo;
  float s = 0.0f, m = -INFINITY;
  for (int row = start; row < end; ++row) {
    float v = h[(long)row * HD + c];
    s += v;
    m = fmaxf(m, v);
  }
  const int cnt = end - start;
  ssum[b * HD + c]  = s;
  smean[b * HD + c] = s / fmaxf((float)cnt, 1.0f);
  smax[b * HD + c]  = (cnt > 0) ? m : 0.0f;
}

// ---------------- order encoder + score head, one block per (b,o) ----------------
__global__ void head_kernel(const float* __restrict__ orders,
                            const float* __restrict__ oW1, const float* __restrict__ ob1,
                            const float* __restrict__ oW2, const float* __restrict__ ob2,
                            const float* __restrict__ sW1, const float* __restrict__ sb1,
                            const float* __restrict__ sW2, const float* __restrict__ sb2,
                            const float* __restrict__ sW3, const float* __restrict__ sb3,
                            const float* __restrict__ smean, const float* __restrict__ smax,
                            const float* __restrict__ ssum, float* __restrict__ out) {
  __shared__ float t1[128];
  __shared__ float comb[512];
  __shared__ float s1[128];
  __shared__ float s2[64];
  const int bo = blockIdx.x;       // b*NO + o
  const int b = bo >> 5;
  const int tid = threadIdx.x;     // 128

  {
    float acc = ob1[tid];
    const float* orow = orders + (long)bo * 32;
    for (int k = 0; k < 32; ++k) acc += orow[k] * oW1[k * 128 + tid];
    t1[tid] = fmaxf(acc, 0.0f);
  }
  comb[tid]       = smean[b * HD + tid];
  comb[128 + tid] = smax[b * HD + tid];
  comb[256 + tid] = ssum[b * HD + tid];
  __syncthreads();
  {
    float acc = ob2[tid];
    for (int k = 0; k < 128; ++k) acc += t1[k] * oW2[k * 128 + tid];
    comb[384 + tid] = acc;
  }
  __syncthreads();
  {
    float acc = sb1[tid];
    for (int k = 0; k < 512; ++k) acc += comb[k] * sW1[k * 128 + tid];
    s1[tid] = fmaxf(acc, 0.0f);
  }
  __syncthreads();
  if (tid < 64) {
    float acc = sb2[tid];
    for (int k = 0; k < 128; ++k) acc += s1[k] * sW2[k * 64 + tid];
    s2[tid] = fmaxf(acc, 0.0f);
  }
  __syncthreads();
  if (tid == 0) {
    float acc = sb3[0];
    for (int k = 0; k < 64; ++k) acc += s2[k] * sW3[k];
    out[bo] = acc;
  }
}

extern "C" void kernel_launch(void* const* d_in, const int* in_sizes, int n_in,
                              void* d_out, int out_size, void* d_ws, size_t ws_size,
                              hipStream_t stream) {
  const float* x      = (const float*)d_in[0];
  const int*   ei     = (const int*)d_in[1];
  const float* orders = (const float*)d_in[2];
  const int*   batch  = (const int*)d_in[3];
  const float* gW1    = (const float*)d_in[4];
  const float* gb1    = (const float*)d_in[5];
  const float* gW2    = (const float*)d_in[6];
  const float* gb2    = (const float*)d_in[7];
  const float* gamma  = (const float*)d_in[8];
  const float* beta   = (const float*)d_in[9];
  const float* oW1    = (const float*)d_in[10];
  const float* ob1    = (const float*)d_in[11];
  const float* oW2    = (const float*)d_in[12];
  const float* ob2    = (const float*)d_in[13];
  const float* sW1    = (const float*)d_in[14];
  const float* sb1    = (const float*)d_in[15];
  const float* sW2    = (const float*)d_in[16];
  const float* sb2    = (const float*)d_in[17];
  const float* sW3    = (const float*)d_in[18];
  const float* sb3    = (const float*)d_in[19];
  float* out = (float*)d_out;

  char* ws = (char*)d_ws;
  float* bufA = (float*)ws;                       // z / out2   [NN,128]
  float* bufC = (float*)(ws + NH * 4);            // hidden / h [NN,128]
  char* small = ws + 2 * NH * 4;
  float* accum = (float*)small;                   // 256
  float* ssbn  = accum + 256;                     // 256 (scale|shift)
  float* ssum  = ssbn + 256;                      // 256*128
  float* smean = ssum + NB * HD;                  // 256*128
  float* smax  = smean + NB * HD;                 // 256*128
  int* rowptr = (int*)(smax + NB * HD);           // NN
  int* col    = rowptr + NN;                      // NE

  // ---- CSR build (by dst), once ----
  hipMemsetAsync(rowptr, 0, NN * sizeof(int), stream);
  hist_kernel<<<(NE + 255) / 256, 256, 0, stream>>>(ei, rowptr);
  scan_kernel<<<1, 1024, 0, stream>>>(rowptr);
  fill_kernel<<<(NE + 255) / 256, 256, 0, stream>>>(ei, rowptr, col);

  const float* hcur = x;
  for (int l = 0; l < 3; ++l) {
    // z = h + sum_neighbors h   (no memset needed; fully overwritten)
    gather_kernel<<<NN / 2, 256, 0, stream>>>(hcur, rowptr, col, bufA);
    // hidden = ReLU(z @ W1 + b1)
    mlp_gemm<true><<<NN / 16, 256, 0, stream>>>(
        bufA, gW1 + (long)l * 128 * 128, gb1 + l * 128, bufC);
    // out2 = hidden @ W2 + b2
    mlp_gemm<false><<<NN / 16, 256, 0, stream>>>(
        bufC, gW2 + (long)l * 128 * 128, gb2 + l * 128, bufA);
    hipMemsetAsync(accum, 0, 256 * sizeof(float), stream);
    bn_stats<<<1024, 128, 0, stream>>>(bufA, accum);
    bn_finalize<<<1, 128, 0, stream>>>(accum, gamma + l * 128, beta + l * 128, ssbn);
    if (l < 2)
      bn_apply<true><<<(NN * 32 + 255) / 256, 256, 0, stream>>>(bufA, ssbn, bufC);
    else
      bn_apply<false><<<(NN * 32 + 255) / 256, 256, 0, stream>>>(bufA, ssbn, bufC);
    hcur = bufC;
  }

  pool_kernel<<<NB, 128, 0, stream>>>(bufC, batch, smean, smax, ssum);
  head_kernel<<<NB * NO, 128, 0, stream>>>(orders, oW1, ob1, oW2, ob2,
                                           sW1, sb1, sW2, sb2, sW3, sb3,
                                           smean, smax, ssum, out);
}

// Round 3
// 1999.267 us; speedup vs baseline: 4.8252x; 1.3524x over previous
//
#include <hip/hip_runtime.h>

static constexpr int NN = 100000;   // nodes
static constexpr int NE = 1600000;  // edges
static constexpr int NB = 256;     // graphs
static constexpr int NO = 32;      // orders per graph
static constexpr int HD = 128;     // hidden dim
static constexpr long NH = (long)NN * HD;

// ---------------- CSR build (once per call; edge_index fixed across layers) ----------------
__global__ void hist_kernel(const int* __restrict__ ei, int* __restrict__ rowptr) {
  int e = blockIdx.x * blockDim.x + threadIdx.x;
  if (e >= NE) return;
  atomicAdd(&rowptr[ei[NE + e]], 1);
}

// in-place exclusive scan of rowptr[0..NN), single block of 1024 threads
__global__ void scan_kernel(int* __restrict__ rowptr) {
  __shared__ int part[1024];
  const int t = threadIdx.x;
  const int C = (NN + 1023) / 1024;
  const int lo = t * C, hi = min(lo + C, NN);
  int s = 0;
  for (int i = lo; i < hi; ++i) s += rowptr[i];
  part[t] = s;
  __syncthreads();
  for (int off = 1; off < 1024; off <<= 1) {
    int v = (t >= off) ? part[t - off] : 0;
    __syncthreads();
    part[t] += v;
    __syncthreads();
  }
  int excl = (t == 0) ? 0 : part[t - 1];
  for (int i = lo; i < hi; ++i) {
    int v = rowptr[i];
    rowptr[i] = excl;
    excl += v;
  }
}

// col[pos] = src; after this kernel rowptr[n] == end offset of node n
__global__ void fill_kernel(const int* __restrict__ ei, int* __restrict__ rowptr,
                            int* __restrict__ col) {
  int e = blockIdx.x * blockDim.x + threadIdx.x;
  if (e >= NE) return;
  int s = ei[e];
  int d = ei[NE + e];
  int pos = atomicAdd(&rowptr[d], 1);
  col[pos] = s;
}

// ---------------- gather: z[n] = h[n] + sum_{j in CSR(n)} h[col[j]] ----------------
__global__ void gather_kernel(const float* __restrict__ h, const int* __restrict__ rowptr,
                              const int* __restrict__ col, float* __restrict__ z) {
  const int node = blockIdx.x * 2 + (threadIdx.x >> 7);
  const int c = threadIdx.x & 127;
  const int lo = (node == 0) ? 0 : rowptr[node - 1];
  const int hi = rowptr[node];
  float acc = h[(long)node * HD + c];
  for (int j = lo; j < hi; ++j) {
    int s = col[j];
    acc += h[(long)s * HD + c];
  }
  z[(long)node * HD + c] = acc;
}

// ---------------- register-tiled fp32 GEMM: out = op(A @ W + b) ----------------
// A: [NN,128], W: [128,128] row-major. Block: 64 rows x 128 cols, 256 threads.
// Thread micro-tile: 4 rows x 8 cols. A staged transposed in LDS (32KB, conflict-free);
// W read from global (64KB, L1/L2-hot across all blocks).
template <bool RELU_OUT, bool BN_STATS>
__global__ void __launch_bounds__(256)
mlp_gemm(const float* __restrict__ A, const float* __restrict__ W,
         const float* __restrict__ bias, float* __restrict__ out,
         float* __restrict__ accum) {
  __shared__ float At[128 * 64];  // At[k*64 + r] = A[row0+r][k]
  __shared__ float red[256];      // BN partial sums: [0..127]=sum, [128..255]=sumsq
  const int row0 = blockIdx.x * 64;
  const int t = threadIdx.x;

  // stage A transposed; lanes consecutive in r -> conflict-free LDS writes
  for (int idx = t; idx < 64 * 32; idx += 256) {
    int r = idx & 63;
    int c4 = (idx >> 6) << 2;
    int row = row0 + r;
    float4 v = make_float4(0.f, 0.f, 0.f, 0.f);
    if (row < NN) v = *reinterpret_cast<const float4*>(&A[(long)row * HD + c4]);
    At[(c4 + 0) * 64 + r] = v.x;
    At[(c4 + 1) * 64 + r] = v.y;
    At[(c4 + 2) * 64 + r] = v.z;
    At[(c4 + 3) * 64 + r] = v.w;
  }
  __syncthreads();

  const int tr = (t & 15) * 4;   // row offset within tile
  const int tc = (t >> 4) * 8;   // col offset
  float bb[8];
  *reinterpret_cast<float4*>(&bb[0]) = *reinterpret_cast<const float4*>(&bias[tc]);
  *reinterpret_cast<float4*>(&bb[4]) = *reinterpret_cast<const float4*>(&bias[tc + 4]);
  float acc[4][8];
#pragma unroll
  for (int i = 0; i < 4; ++i)
#pragma unroll
    for (int j = 0; j < 8; ++j) acc[i][j] = bb[j];

#pragma unroll 4
  for (int k = 0; k < 128; ++k) {
    float a[4], w[8];
    *reinterpret_cast<float4*>(&a[0]) = *reinterpret_cast<const float4*>(&At[k * 64 + tr]);
    *reinterpret_cast<float4*>(&w[0]) = *reinterpret_cast<const float4*>(&W[k * 128 + tc]);
    *reinterpret_cast<float4*>(&w[4]) = *reinterpret_cast<const float4*>(&W[k * 128 + tc + 4]);
#pragma unroll
    for (int i = 0; i < 4; ++i)
#pragma unroll
      for (int j = 0; j < 8; ++j) acc[i][j] = fmaf(a[i], w[j], acc[i][j]);
  }

  float s[8], q[8];
  if (BN_STATS) {
#pragma unroll
    for (int j = 0; j < 8; ++j) { s[j] = 0.f; q[j] = 0.f; }
  }
#pragma unroll
  for (int i = 0; i < 4; ++i) {
    int row = row0 + tr + i;
    if (row < NN) {
      float o[8];
#pragma unroll
      for (int j = 0; j < 8; ++j) {
        float v = acc[i][j];
        if (RELU_OUT) v = fmaxf(v, 0.f);
        o[j] = v;
        if (BN_STATS) { s[j] += v; q[j] += v * v; }
      }
      *reinterpret_cast<float4*>(&out[(long)row * HD + tc])     = *reinterpret_cast<float4*>(&o[0]);
      *reinterpret_cast<float4*>(&out[(long)row * HD + tc + 4]) = *reinterpret_cast<float4*>(&o[4]);
    }
  }

  if (BN_STATS) {
    red[t] = 0.f;
    __syncthreads();
#pragma unroll
    for (int j = 0; j < 8; ++j) {
      atomicAdd(&red[tc + j], s[j]);
      atomicAdd(&red[128 + tc + j], q[j]);
    }
    __syncthreads();
    atomicAdd(&accum[t], red[t]);
  }
}

// ---------------- batchnorm finalize / apply ----------------
__global__ void bn_finalize(const float* __restrict__ accum, const float* __restrict__ gamma,
                            const float* __restrict__ beta, float* __restrict__ ss) {
  const int c = threadIdx.x;  // 128
  const float n = (float)NN;
  float mu  = accum[c] / n;
  float var = accum[128 + c] / n - mu * mu;
  float rstd = rsqrtf(var + 1e-5f);
  float sc = rstd * gamma[c];
  ss[c] = sc;
  ss[128 + c] = beta[c] - mu * sc;
}

template <bool RELU>
__global__ void bn_apply(const float* __restrict__ z, const float* __restrict__ ss,
                         float* __restrict__ out) {
  int idx = blockIdx.x * blockDim.x + threadIdx.x;
  if (idx >= NN * 32) return;  // 4 floats per thread
  int c4 = (idx & 31) << 2;
  const float4 v = *reinterpret_cast<const float4*>(z + (long)idx * 4);
  float4 r;
  r.x = v.x * ss[c4 + 0] + ss[128 + c4 + 0];
  r.y = v.y * ss[c4 + 1] + ss[128 + c4 + 1];
  r.z = v.z * ss[c4 + 2] + ss[128 + c4 + 2];
  r.w = v.w * ss[c4 + 3] + ss[128 + c4 + 3];
  if (RELU) {
    r.x = fmaxf(r.x, 0.0f); r.y = fmaxf(r.y, 0.0f);
    r.z = fmaxf(r.z, 0.0f); r.w = fmaxf(r.w, 0.0f);
  }
  *reinterpret_cast<float4*>(out + (long)idx * 4) = r;
}

// ---------------- pooling: batch is sorted -> segment scan per graph ----------------
__global__ void pool_kernel(const float* __restrict__ h, const int* __restrict__ batch,
                            float* __restrict__ smean, float* __restrict__ smax,
                            float* __restrict__ ssum) {
  const int b = blockIdx.x;   // 256
  const int c = threadIdx.x;  // 128
  int lo = 0, hi = NN;
  while (lo < hi) { int mid = (lo + hi) >> 1; if (batch[mid] < b) lo = mid + 1; else hi = mid; }
  const int start = lo;
  hi = NN;
  while (lo < hi) { int mid = (lo + hi) >> 1; if (batch[mid] < b + 1) lo = mid + 1; else hi = mid; }
  const int end = lo;
  float s = 0.0f, m = -INFINITY;
  for (int row = start; row < end; ++row) {
    float v = h[(long)row * HD + c];
    s += v;
    m = fmaxf(m, v);
  }
  const int cnt = end - start;
  ssum[b * HD + c]  = s;
  smean[b * HD + c] = s / fmaxf((float)cnt, 1.0f);
  smax[b * HD + c]  = (cnt > 0) ? m : 0.0f;
}

// ---------------- order encoder + score head, one block per (b,o) ----------------
__global__ void head_kernel(const float* __restrict__ orders,
                            const float* __restrict__ oW1, const float* __restrict__ ob1,
                            const float* __restrict__ oW2, const float* __restrict__ ob2,
                            const float* __restrict__ sW1, const float* __restrict__ sb1,
                            const float* __restrict__ sW2, const float* __restrict__ sb2,
                            const float* __restrict__ sW3, const float* __restrict__ sb3,
                            const float* __restrict__ smean, const float* __restrict__ smax,
                            const float* __restrict__ ssum, float* __restrict__ out) {
  __shared__ float t1[128];
  __shared__ float comb[512];
  __shared__ float s1[128];
  __shared__ float s2[64];
  const int bo = blockIdx.x;       // b*NO + o
  const int b = bo >> 5;
  const int tid = threadIdx.x;     // 128

  {
    float acc = ob1[tid];
    const float* orow = orders + (long)bo * 32;
    for (int k = 0; k < 32; ++k) acc += orow[k] * oW1[k * 128 + tid];
    t1[tid] = fmaxf(acc, 0.0f);
  }
  comb[tid]       = smean[b * HD + tid];
  comb[128 + tid] = smax[b * HD + tid];
  comb[256 + tid] = ssum[b * HD + tid];
  __syncthreads();
  {
    float acc = ob2[tid];
    for (int k = 0; k < 128; ++k) acc += t1[k] * oW2[k * 128 + tid];
    comb[384 + tid] = acc;
  }
  __syncthreads();
  {
    float acc = sb1[tid];
    for (int k = 0; k < 512; ++k) acc += comb[k] * sW1[k * 128 + tid];
    s1[tid] = fmaxf(acc, 0.0f);
  }
  __syncthreads();
  if (tid < 64) {
    float acc = sb2[tid];
    for (int k = 0; k < 128; ++k) acc += s1[k] * sW2[k * 64 + tid];
    s2[tid] = fmaxf(acc, 0.0f);
  }
  __syncthreads();
  if (tid == 0) {
    float acc = sb3[0];
    for (int k = 0; k < 64; ++k) acc += s2[k] * sW3[k];
    out[bo] = acc;
  }
}

extern "C" void kernel_launch(void* const* d_in, const int* in_sizes, int n_in,
                              void* d_out, int out_size, void* d_ws, size_t ws_size,
                              hipStream_t stream) {
  const float* x      = (const float*)d_in[0];
  const int*   ei     = (const int*)d_in[1];
  const float* orders = (const float*)d_in[2];
  const int*   batch  = (const int*)d_in[3];
  const float* gW1    = (const float*)d_in[4];
  const float* gb1    = (const float*)d_in[5];
  const float* gW2    = (const float*)d_in[6];
  const float* gb2    = (const float*)d_in[7];
  const float* gamma  = (const float*)d_in[8];
  const float* beta   = (const float*)d_in[9];
  const float* oW1    = (const float*)d_in[10];
  const float* ob1    = (const float*)d_in[11];
  const float* oW2    = (const float*)d_in[12];
  const float* ob2    = (const float*)d_in[13];
  const float* sW1    = (const float*)d_in[14];
  const float* sb1    = (const float*)d_in[15];
  const float* sW2    = (const float*)d_in[16];
  const float* sb2    = (const float*)d_in[17];
  const float* sW3    = (const float*)d_in[18];
  const float* sb3    = (const float*)d_in[19];
  float* out = (float*)d_out;

  char* ws = (char*)d_ws;
  float* bufA = (float*)ws;                       // z / out2   [NN,128]
  float* bufC = (float*)(ws + NH * 4);            // hidden / h [NN,128]
  char* small = ws + 2 * NH * 4;
  float* accum = (float*)small;                   // 256
  float* ssbn  = accum + 256;                     // 256 (scale|shift)
  float* ssum  = ssbn + 256;                      // 256*128
  float* smean = ssum + NB * HD;                  // 256*128
  float* smax  = smean + NB * HD;                 // 256*128
  int* rowptr = (int*)(smax + NB * HD);           // NN
  int* col    = rowptr + NN;                      // NE

  // ---- CSR build (by dst), once ----
  hipMemsetAsync(rowptr, 0, NN * sizeof(int), stream);
  hist_kernel<<<(NE + 255) / 256, 256, 0, stream>>>(ei, rowptr);
  scan_kernel<<<1, 1024, 0, stream>>>(rowptr);
  fill_kernel<<<(NE + 255) / 256, 256, 0, stream>>>(ei, rowptr, col);

  const int GEMM_GRID = (NN + 63) / 64;
  const float* hcur = x;
  for (int l = 0; l < 3; ++l) {
    // z = h + sum_neighbors h
    gather_kernel<<<NN / 2, 256, 0, stream>>>(hcur, rowptr, col, bufA);
    // hidden = ReLU(z @ W1 + b1)
    mlp_gemm<true, false><<<GEMM_GRID, 256, 0, stream>>>(
        bufA, gW1 + (long)l * 128 * 128, gb1 + l * 128, bufC, nullptr);
    // out2 = hidden @ W2 + b2, fused BN stats
    hipMemsetAsync(accum, 0, 256 * sizeof(float), stream);
    mlp_gemm<false, true><<<GEMM_GRID, 256, 0, stream>>>(
        bufC, gW2 + (long)l * 128 * 128, gb2 + l * 128, bufA, accum);
    bn_finalize<<<1, 128, 0, stream>>>(accum, gamma + l * 128, beta + l * 128, ssbn);
    if (l < 2)
      bn_apply<true><<<(NN * 32 + 255) / 256, 256, 0, stream>>>(bufA, ssbn, bufC);
    else
      bn_apply<false><<<(NN * 32 + 255) / 256, 256, 0, stream>>>(bufA, ssbn, bufC);
    hcur = bufC;
  }

  pool_kernel<<<NB, 128, 0, stream>>>(bufC, batch, smean, smax, ssum);
  head_kernel<<<NB * NO, 128, 0, stream>>>(orders, oW1, ob1, oW2, ob2,
                                           sW1, sb1, sW2, sb2, sW3, sb3,
                                           smean, smax, ssum, out);
}

// Round 4
// 1473.615 us; speedup vs baseline: 6.5464x; 1.3567x over previous
//
#include <hip/hip_runtime.h>

static constexpr int NN = 100000;   // nodes
static constexpr int NE = 1600000;  // edges
static constexpr int NB = 256;     // graphs
static constexpr int NO = 32;      // orders per graph
static constexpr int HD = 128;     // hidden dim
static constexpr long NH = (long)NN * HD;

// ---------------- CSR build (once per call; edge_index fixed across layers) ----------------
__global__ void hist_kernel(const int* __restrict__ ei, int* __restrict__ rowptr) {
  int e = blockIdx.x * blockDim.x + threadIdx.x;
  if (e >= NE) return;
  atomicAdd(&rowptr[ei[NE + e]], 1);
}

// in-place exclusive scan of rowptr[0..NN), single block of 1024 threads
__global__ void scan_kernel(int* __restrict__ rowptr) {
  __shared__ int part[1024];
  const int t = threadIdx.x;
  const int C = (NN + 1023) / 1024;
  const int lo = t * C, hi = min(lo + C, NN);
  int s = 0;
  for (int i = lo; i < hi; ++i) s += rowptr[i];
  part[t] = s;
  __syncthreads();
  for (int off = 1; off < 1024; off <<= 1) {
    int v = (t >= off) ? part[t - off] : 0;
    __syncthreads();
    part[t] += v;
    __syncthreads();
  }
  int excl = (t == 0) ? 0 : part[t - 1];
  for (int i = lo; i < hi; ++i) {
    int v = rowptr[i];
    rowptr[i] = excl;
    excl += v;
  }
}

// col[pos] = src; after this kernel rowptr[n] == end offset of node n
__global__ void fill_kernel(const int* __restrict__ ei, int* __restrict__ rowptr,
                            int* __restrict__ col) {
  int e = blockIdx.x * blockDim.x + threadIdx.x;
  if (e >= NE) return;
  int s = ei[e];
  int d = ei[NE + e];
  int pos = atomicAdd(&rowptr[d], 1);
  col[pos] = s;
}

// ---------------- gather: z[n] = f(hin[n]) + sum_j f(hin[col[j]]), f = optional BN(+ReLU) ----
// one wave per node; lane owns 2 columns (float2); neighbor loop unrolled x4 (4 loads in flight)
template <bool BN, bool RELU>
__global__ void gather_kernel(const float* __restrict__ hin, const int* __restrict__ rowptr,
                              const int* __restrict__ col, const float* __restrict__ ss,
                              float* __restrict__ z) {
  const int node = (blockIdx.x * blockDim.x + threadIdx.x) >> 6;
  if (node >= NN) return;
  const int c2 = (threadIdx.x & 63) * 2;
  float scx = 1.f, scy = 1.f, shx = 0.f, shy = 0.f;
  if (BN) {
    float2 sc = *reinterpret_cast<const float2*>(ss + c2);
    float2 sh = *reinterpret_cast<const float2*>(ss + 128 + c2);
    scx = sc.x; scy = sc.y; shx = sh.x; shy = sh.y;
  }
  auto ldh = [&](int n) -> float2 {
    float2 v = *reinterpret_cast<const float2*>(hin + (long)n * HD + c2);
    if (BN) {
      v.x = fmaf(v.x, scx, shx);
      v.y = fmaf(v.y, scy, shy);
      if (RELU) { v.x = fmaxf(v.x, 0.f); v.y = fmaxf(v.y, 0.f); }
    }
    return v;
  };
  const int lo = (node == 0) ? 0 : rowptr[node - 1];
  const int hi = rowptr[node];
  float2 acc = ldh(node);
  int j = lo;
  for (; j + 4 <= hi; j += 4) {
    int s0 = col[j], s1 = col[j + 1], s2 = col[j + 2], s3 = col[j + 3];
    float2 v0 = ldh(s0), v1 = ldh(s1), v2 = ldh(s2), v3 = ldh(s3);
    acc.x += (v0.x + v1.x) + (v2.x + v3.x);
    acc.y += (v0.y + v1.y) + (v2.y + v3.y);
  }
  if (j < hi) {  // masked 4-wide tail: keep loads independent, zero-weight the pad
    int last = hi - 1;
    int s0 = col[j];
    int s1 = col[min(j + 1, last)];
    int s2 = col[min(j + 2, last)];
    int s3 = col[min(j + 3, last)];
    float m1 = (j + 1 < hi) ? 1.f : 0.f;
    float m2 = (j + 2 < hi) ? 1.f : 0.f;
    float m3 = (j + 3 < hi) ? 1.f : 0.f;
    float2 v0 = ldh(s0), v1 = ldh(s1), v2 = ldh(s2), v3 = ldh(s3);
    acc.x += v0.x + m1 * v1.x + m2 * v2.x + m3 * v3.x;
    acc.y += v0.y + m1 * v1.y + m2 * v2.y + m3 * v3.y;
  }
  *reinterpret_cast<float2*>(z + (long)node * HD + c2) = acc;
}

// ---------------- register-tiled fp32 GEMM: out = op(A @ W + b) ----------------
// A: [NN,128], W: [128,128] row-major. Block: 64 rows x 128 cols, 256 threads.
// In-place safe (out may == A): rows staged to LDS before any write.
template <bool RELU_OUT, bool BN_STATS>
__global__ void __launch_bounds__(256)
mlp_gemm(const float* __restrict__ A, const float* __restrict__ W,
         const float* __restrict__ bias, float* __restrict__ out,
         float* __restrict__ accum) {
  __shared__ float At[128 * 64];  // At[k*64 + r] = A[row0+r][k]
  __shared__ float red[256];      // BN partial sums: [0..127]=sum, [128..255]=sumsq
  const int row0 = blockIdx.x * 64;
  const int t = threadIdx.x;

  for (int idx = t; idx < 64 * 32; idx += 256) {
    int r = idx & 63;
    int c4 = (idx >> 6) << 2;
    int row = row0 + r;
    float4 v = make_float4(0.f, 0.f, 0.f, 0.f);
    if (row < NN) v = *reinterpret_cast<const float4*>(&A[(long)row * HD + c4]);
    At[(c4 + 0) * 64 + r] = v.x;
    At[(c4 + 1) * 64 + r] = v.y;
    At[(c4 + 2) * 64 + r] = v.z;
    At[(c4 + 3) * 64 + r] = v.w;
  }
  __syncthreads();

  const int tr = (t & 15) * 4;   // row offset within tile
  const int tc = (t >> 4) * 8;   // col offset
  float bb[8];
  *reinterpret_cast<float4*>(&bb[0]) = *reinterpret_cast<const float4*>(&bias[tc]);
  *reinterpret_cast<float4*>(&bb[4]) = *reinterpret_cast<const float4*>(&bias[tc + 4]);
  float acc[4][8];
#pragma unroll
  for (int i = 0; i < 4; ++i)
#pragma unroll
    for (int j = 0; j < 8; ++j) acc[i][j] = bb[j];

#pragma unroll 4
  for (int k = 0; k < 128; ++k) {
    float a[4], w[8];
    *reinterpret_cast<float4*>(&a[0]) = *reinterpret_cast<const float4*>(&At[k * 64 + tr]);
    *reinterpret_cast<float4*>(&w[0]) = *reinterpret_cast<const float4*>(&W[k * 128 + tc]);
    *reinterpret_cast<float4*>(&w[4]) = *reinterpret_cast<const float4*>(&W[k * 128 + tc + 4]);
#pragma unroll
    for (int i = 0; i < 4; ++i)
#pragma unroll
      for (int j = 0; j < 8; ++j) acc[i][j] = fmaf(a[i], w[j], acc[i][j]);
  }

  float s[8], q[8];
  if (BN_STATS) {
#pragma unroll
    for (int j = 0; j < 8; ++j) { s[j] = 0.f; q[j] = 0.f; }
  }
#pragma unroll
  for (int i = 0; i < 4; ++i) {
    int row = row0 + tr + i;
    if (row < NN) {
      float o[8];
#pragma unroll
      for (int j = 0; j < 8; ++j) {
        float v = acc[i][j];
        if (RELU_OUT) v = fmaxf(v, 0.f);
        o[j] = v;
        if (BN_STATS) { s[j] += v; q[j] += v * v; }
      }
      *reinterpret_cast<float4*>(&out[(long)row * HD + tc])     = *reinterpret_cast<float4*>(&o[0]);
      *reinterpret_cast<float4*>(&out[(long)row * HD + tc + 4]) = *reinterpret_cast<float4*>(&o[4]);
    }
  }

  if (BN_STATS) {
    red[t] = 0.f;
    __syncthreads();
#pragma unroll
    for (int j = 0; j < 8; ++j) {
      atomicAdd(&red[tc + j], s[j]);
      atomicAdd(&red[128 + tc + j], q[j]);
    }
    __syncthreads();
    atomicAdd(&accum[t], red[t]);
  }
}

// ---------------- batchnorm finalize: scale/shift from accumulated stats ----------------
__global__ void bn_finalize(const float* __restrict__ accum, const float* __restrict__ gamma,
                            const float* __restrict__ beta, float* __restrict__ ss) {
  const int c = threadIdx.x;  // 128
  const float n = (float)NN;
  float mu  = accum[c] / n;
  float var = accum[128 + c] / n - mu * mu;
  float rstd = rsqrtf(var + 1e-5f);
  float sc = rstd * gamma[c];
  ss[c] = sc;
  ss[128 + c] = beta[c] - mu * sc;
}

// ---------------- pooling with fused BN (no relu): batch sorted -> segment scan ----------------
__global__ void pool_kernel(const float* __restrict__ z2, const float* __restrict__ ss,
                            const int* __restrict__ batch,
                            float* __restrict__ smean, float* __restrict__ smax,
                            float* __restrict__ ssum) {
  const int b = blockIdx.x;   // 256
  const int c = threadIdx.x;  // 128
  const float sc = ss[c];
  const float sh = ss[128 + c];
  int lo = 0, hi = NN;
  while (lo < hi) { int mid = (lo + hi) >> 1; if (batch[mid] < b) lo = mid + 1; else hi = mid; }
  const int start = lo;
  hi = NN;
  while (lo < hi) { int mid = (lo + hi) >> 1; if (batch[mid] < b + 1) lo = mid + 1; else hi = mid; }
  const int end = lo;
  float s = 0.0f, m = -INFINITY;
  for (int row = start; row < end; ++row) {
    float v = fmaf(z2[(long)row * HD + c], sc, sh);
    s += v;
    m = fmaxf(m, v);
  }
  const int cnt = end - start;
  ssum[b * HD + c]  = s;
  smean[b * HD + c] = s / fmaxf((float)cnt, 1.0f);
  smax[b * HD + c]  = (cnt > 0) ? m : 0.0f;
}

// ---------------- order encoder + score head, one block per (b,o) ----------------
__global__ void head_kernel(const float* __restrict__ orders,
                            const float* __restrict__ oW1, const float* __restrict__ ob1,
                            const float* __restrict__ oW2, const float* __restrict__ ob2,
                            const float* __restrict__ sW1, const float* __restrict__ sb1,
                            const float* __restrict__ sW2, const float* __restrict__ sb2,
                            const float* __restrict__ sW3, const float* __restrict__ sb3,
                            const float* __restrict__ smean, const float* __restrict__ smax,
                            const float* __restrict__ ssum, float* __restrict__ out) {
  __shared__ float t1[128];
  __shared__ float comb[512];
  __shared__ float s1[128];
  __shared__ float s2[64];
  const int bo = blockIdx.x;       // b*NO + o
  const int b = bo >> 5;
  const int tid = threadIdx.x;     // 128

  {
    float acc = ob1[tid];
    const float* orow = orders + (long)bo * 32;
    for (int k = 0; k < 32; ++k) acc += orow[k] * oW1[k * 128 + tid];
    t1[tid] = fmaxf(acc, 0.0f);
  }
  comb[tid]       = smean[b * HD + tid];
  comb[128 + tid] = smax[b * HD + tid];
  comb[256 + tid] = ssum[b * HD + tid];
  __syncthreads();
  {
    float acc = ob2[tid];
    for (int k = 0; k < 128; ++k) acc += t1[k] * oW2[k * 128 + tid];
    comb[384 + tid] = acc;
  }
  __syncthreads();
  {
    float acc = sb1[tid];
    for (int k = 0; k < 512; ++k) acc += comb[k] * sW1[k * 128 + tid];
    s1[tid] = fmaxf(acc, 0.0f);
  }
  __syncthreads();
  if (tid < 64) {
    float acc = sb2[tid];
    for (int k = 0; k < 128; ++k) acc += s1[k] * sW2[k * 64 + tid];
    s2[tid] = fmaxf(acc, 0.0f);
  }
  __syncthreads();
  if (tid == 0) {
    float acc = sb3[0];
    for (int k = 0; k < 64; ++k) acc += s2[k] * sW3[k];
    out[bo] = acc;
  }
}

extern "C" void kernel_launch(void* const* d_in, const int* in_sizes, int n_in,
                              void* d_out, int out_size, void* d_ws, size_t ws_size,
                              hipStream_t stream) {
  const float* x      = (const float*)d_in[0];
  const int*   ei     = (const int*)d_in[1];
  const float* orders = (const float*)d_in[2];
  const int*   batch  = (const int*)d_in[3];
  const float* gW1    = (const float*)d_in[4];
  const float* gb1    = (const float*)d_in[5];
  const float* gW2    = (const float*)d_in[6];
  const float* gb2    = (const float*)d_in[7];
  const float* gamma  = (const float*)d_in[8];
  const float* beta   = (const float*)d_in[9];
  const float* oW1    = (const float*)d_in[10];
  const float* ob1    = (const float*)d_in[11];
  const float* oW2    = (const float*)d_in[12];
  const float* ob2    = (const float*)d_in[13];
  const float* sW1    = (const float*)d_in[14];
  const float* sb1    = (const float*)d_in[15];
  const float* sW2    = (const float*)d_in[16];
  const float* sb2    = (const float*)d_in[17];
  const float* sW3    = (const float*)d_in[18];
  const float* sb3    = (const float*)d_in[19];
  float* out = (float*)d_out;

  char* ws = (char*)d_ws;
  float* bufA = (float*)ws;                       // z / hidden (GEMM1 in-place) [NN,128]
  float* bufC = (float*)(ws + NH * 4);            // z2 (pre-BN)                 [NN,128]
  char* small = ws + 2 * NH * 4;
  float* accum = (float*)small;                   // 256
  float* ssbn  = accum + 256;                     // 256 (scale|shift)
  float* ssum  = ssbn + 256;                      // 256*128
  float* smean = ssum + NB * HD;                  // 256*128
  float* smax  = smean + NB * HD;                 // 256*128
  int* rowptr = (int*)(smax + NB * HD);           // NN
  int* col    = rowptr + NN;                      // NE

  // ---- CSR build (by dst), once ----
  hipMemsetAsync(rowptr, 0, NN * sizeof(int), stream);
  hist_kernel<<<(NE + 255) / 256, 256, 0, stream>>>(ei, rowptr);
  scan_kernel<<<1, 1024, 0, stream>>>(rowptr);
  fill_kernel<<<(NE + 255) / 256, 256, 0, stream>>>(ei, rowptr, col);

  const int GEMM_GRID = (NN + 63) / 64;
  const int GATHER_GRID = NN / 4;  // 4 waves (nodes) per 256-thread block
  for (int l = 0; l < 3; ++l) {
    // z = f(h) + sum_neighbors f(h);  f = id (l=0) or BN+ReLU of previous layer's z2
    if (l == 0)
      gather_kernel<false, false><<<GATHER_GRID, 256, 0, stream>>>(x, rowptr, col, ssbn, bufA);
    else
      gather_kernel<true, true><<<GATHER_GRID, 256, 0, stream>>>(bufC, rowptr, col, ssbn, bufA);
    // hidden = ReLU(z @ W1 + b1)  (in-place over bufA)
    mlp_gemm<true, false><<<GEMM_GRID, 256, 0, stream>>>(
        bufA, gW1 + (long)l * 128 * 128, gb1 + l * 128, bufA, nullptr);
    // z2 = hidden @ W2 + b2, fused BN stats
    hipMemsetAsync(accum, 0, 256 * sizeof(float), stream);
    mlp_gemm<false, true><<<GEMM_GRID, 256, 0, stream>>>(
        bufA, gW2 + (long)l * 128 * 128, gb2 + l * 128, bufC, accum);
    bn_finalize<<<1, 128, 0, stream>>>(accum, gamma + l * 128, beta + l * 128, ssbn);
  }

  // pooling reads z2 of layer 2 with BN applied on the fly (no relu on last layer)
  pool_kernel<<<NB, 128, 0, stream>>>(bufC, ssbn, batch, smean, smax, ssum);
  head_kernel<<<NB * NO, 128, 0, stream>>>(orders, oW1, ob1, oW2, ob2,
                                           sW1, sb1, sW2, sb2, sW3, sb3,
                                           smean, smax, ssum, out);
}

// Round 5
// 1025.653 us; speedup vs baseline: 9.4055x; 1.4368x over previous
//
#include <hip/hip_runtime.h>

static constexpr int NN = 100000;   // nodes
static constexpr int NE = 1600000;  // edges
static constexpr int NB = 256;     // graphs
static constexpr int NO = 32;      // orders per graph
static constexpr int HD = 128;     // hidden dim
static constexpr long NH = (long)NN * HD;
static constexpr int NBLK_SCAN = (NN + 255) / 256;  // 391

typedef __bf16 bf16x8 __attribute__((ext_vector_type(8)));
typedef float f32x4 __attribute__((ext_vector_type(4)));
typedef short short8 __attribute__((ext_vector_type(8)));

__device__ __forceinline__ unsigned short f2bf(float f) {
  unsigned int u = __builtin_bit_cast(unsigned int, f);
  u += 0x7FFFu + ((u >> 16) & 1u);  // RNE
  return (unsigned short)(u >> 16);
}

// ---------------- CSR build ----------------
__global__ void hist_kernel(const int* __restrict__ ei, int* __restrict__ cnt) {
  int e = blockIdx.x * blockDim.x + threadIdx.x;
  if (e >= NE) return;
  atomicAdd(&cnt[ei[NE + e]], 1);
}

__global__ void bsum_kernel(const int* __restrict__ cnt, int* __restrict__ bsum) {
  __shared__ int sh[256];
  int gid = blockIdx.x * 256 + threadIdx.x;
  sh[threadIdx.x] = (gid < NN) ? cnt[gid] : 0;
  __syncthreads();
  for (int off = 128; off > 0; off >>= 1) {
    if (threadIdx.x < off) sh[threadIdx.x] += sh[threadIdx.x + off];
    __syncthreads();
  }
  if (threadIdx.x == 0) bsum[blockIdx.x] = sh[0];
}

__global__ void bscan_kernel(int* __restrict__ bsum) {
  __shared__ int part[1024];
  int t = threadIdx.x;
  int v = (t < NBLK_SCAN) ? bsum[t] : 0;
  part[t] = v;
  __syncthreads();
  for (int off = 1; off < 1024; off <<= 1) {
    int u = (t >= off) ? part[t - off] : 0;
    __syncthreads();
    part[t] += u;
    __syncthreads();
  }
  if (t < NBLK_SCAN) bsum[t] = part[t] - v;  // exclusive
}

__global__ void local_scan_kernel(const int* __restrict__ cnt, const int* __restrict__ bsum,
                                  int* __restrict__ rowptr) {
  __shared__ int part[256];
  int t = threadIdx.x;
  int gid = blockIdx.x * 256 + t;
  int v = (gid < NN) ? cnt[gid] : 0;
  part[t] = v;
  __syncthreads();
  for (int off = 1; off < 256; off <<= 1) {
    int u = (t >= off) ? part[t - off] : 0;
    __syncthreads();
    part[t] += u;
    __syncthreads();
  }
  if (gid < NN) rowptr[gid] = part[t] - v + bsum[blockIdx.x];
}

// after this kernel rowptr[n] == end offset of node n
__global__ void fill_kernel(const int* __restrict__ ei, int* __restrict__ rowptr,
                            int* __restrict__ col) {
  int e = blockIdx.x * blockDim.x + threadIdx.x;
  if (e >= NE) return;
  int s = ei[e];
  int d = ei[NE + e];
  int pos = atomicAdd(&rowptr[d], 1);
  col[pos] = s;
}

// ---------------- weight packing: fp32 W[128][128] -> bf16 MFMA B-fragments ----------------
// Wp[layer][which][tile t][kstep s][lane][8]; lane holds W[s*32+(lane>>4)*8+j][t*16+(lane&15)]
__global__ void pack_w_kernel(const float* __restrict__ gW1, const float* __restrict__ gW2,
                              unsigned short* __restrict__ Wp) {
  int tid = blockIdx.x * blockDim.x + threadIdx.x;  // 3*2*8*4*64 = 12288
  if (tid >= 12288) return;
  int lane = tid & 63;
  int s = (tid >> 6) & 3;
  int t = (tid >> 8) & 7;
  int which = (tid >> 11) & 1;
  int layer = tid >> 12;
  const float* W = (which ? gW2 : gW1) + (long)layer * 128 * 128;
  unsigned short* dst = Wp + (long)tid * 8;
  int kbase = s * 32 + ((lane >> 4) << 3);
  int n = t * 16 + (lane & 15);
#pragma unroll
  for (int j = 0; j < 8; ++j) dst[j] = f2bf(W[(kbase + j) * 128 + n]);
}

// ---------------- gather: z[n] = f(hin[n]) + sum_j f(hin[col[j]]) ----------------
template <bool BN, bool RELU>
__global__ void gather_kernel(const float* __restrict__ hin, const int* __restrict__ rowptr,
                              const int* __restrict__ col, const float* __restrict__ ss,
                              float* __restrict__ z) {
  const int node = (blockIdx.x * blockDim.x + threadIdx.x) >> 6;
  if (node >= NN) return;
  const int c2 = (threadIdx.x & 63) * 2;
  float scx = 1.f, scy = 1.f, shx = 0.f, shy = 0.f;
  if (BN) {
    float2 sc = *reinterpret_cast<const float2*>(ss + c2);
    float2 sh = *reinterpret_cast<const float2*>(ss + 128 + c2);
    scx = sc.x; scy = sc.y; shx = sh.x; shy = sh.y;
  }
  auto ldh = [&](int n) -> float2 {
    float2 v = *reinterpret_cast<const float2*>(hin + (long)n * HD + c2);
    if (BN) {
      v.x = fmaf(v.x, scx, shx);
      v.y = fmaf(v.y, scy, shy);
      if (RELU) { v.x = fmaxf(v.x, 0.f); v.y = fmaxf(v.y, 0.f); }
    }
    return v;
  };
  const int lo = (node == 0) ? 0 : rowptr[node - 1];
  const int hi = rowptr[node];
  float2 acc = ldh(node);
  int j = lo;
  for (; j + 4 <= hi; j += 4) {
    int s0 = col[j], s1 = col[j + 1], s2 = col[j + 2], s3 = col[j + 3];
    float2 v0 = ldh(s0), v1 = ldh(s1), v2 = ldh(s2), v3 = ldh(s3);
    acc.x += (v0.x + v1.x) + (v2.x + v3.x);
    acc.y += (v0.y + v1.y) + (v2.y + v3.y);
  }
  if (j < hi) {
    int last = hi - 1;
    int s0 = col[j];
    int s1 = col[min(j + 1, last)];
    int s2 = col[min(j + 2, last)];
    int s3 = col[min(j + 3, last)];
    float m1 = (j + 1 < hi) ? 1.f : 0.f;
    float m2 = (j + 2 < hi) ? 1.f : 0.f;
    float m3 = (j + 3 < hi) ? 1.f : 0.f;
    float2 v0 = ldh(s0), v1 = ldh(s1), v2 = ldh(s2), v3 = ldh(s3);
    acc.x += v0.x + m1 * v1.x + m2 * v2.x + m3 * v3.x;
    acc.y += v0.y + m1 * v1.y + m2 * v2.y + m3 * v3.y;
  }
  *reinterpret_cast<float2*>(z + (long)node * HD + c2) = acc;
}

// ---------------- fused GIN layer: z2 = (ReLU(z@W1+b1))@W2 + b2, BN stats fused ----------------
// 64 rows/block, 256 threads = 4 waves; wave w owns rows [w*16, w*16+16).
// MFMA 16x16x32 bf16. hidden round-trips through wave-local LDS (no barrier needed).
__global__ void __launch_bounds__(256)
fused_layer(const float* __restrict__ Z, const unsigned short* __restrict__ Wp,
            const float* __restrict__ b1, const float* __restrict__ b2,
            float* __restrict__ Z2, float* __restrict__ accum) {
  __shared__ unsigned short Abuf[64 * 136];
  __shared__ unsigned short Hbuf[64 * 136];
  __shared__ float red[256];
  const int t = threadIdx.x;
  const int row0 = blockIdx.x * 64;
  const int lane = t & 63;
  const int w = t >> 6;
  const int l15 = lane & 15;
  const int kgrp = lane >> 4;

  // stage Z -> bf16 LDS (row stride 136 to spread banks)
  for (int idx = t; idx < 64 * 32; idx += 256) {
    int r = idx >> 5;
    int c = (idx & 31) * 4;
    int row = row0 + r;
    float4 v = make_float4(0.f, 0.f, 0.f, 0.f);
    if (row < NN) v = *reinterpret_cast<const float4*>(Z + (long)row * HD + c);
    ushort4 h;
    h.x = f2bf(v.x); h.y = f2bf(v.y); h.z = f2bf(v.z); h.w = f2bf(v.w);
    *reinterpret_cast<ushort4*>(&Abuf[r * 136 + c]) = h;
  }
  red[t] = 0.f;
  __syncthreads();

  f32x4 acc[8];
  // ---- GEMM1: hidden = ReLU(A @ W1 + b1) ----
  {
    short8 af[4];
#pragma unroll
    for (int s = 0; s < 4; ++s)
      af[s] = *reinterpret_cast<const short8*>(&Abuf[(w * 16 + l15) * 136 + s * 32 + kgrp * 8]);
    const unsigned short* W1p = Wp;
#pragma unroll
    for (int tt = 0; tt < 8; ++tt) {
      float bb = b1[tt * 16 + l15];
      acc[tt] = (f32x4){bb, bb, bb, bb};
#pragma unroll
      for (int s = 0; s < 4; ++s) {
        bf16x8 bf = *reinterpret_cast<const bf16x8*>(W1p + ((tt * 4 + s) * 64 + lane) * 8);
        acc[tt] = __builtin_amdgcn_mfma_f32_16x16x32_bf16(
            __builtin_bit_cast(bf16x8, af[s]), bf, acc[tt], 0, 0, 0);
      }
    }
  }
  // hidden -> bf16 LDS (wave-local rows; no barrier)
#pragma unroll
  for (int tt = 0; tt < 8; ++tt) {
#pragma unroll
    for (int j = 0; j < 4; ++j) {
      float v = fmaxf(acc[tt][j], 0.f);
      Hbuf[(w * 16 + kgrp * 4 + j) * 136 + tt * 16 + l15] = f2bf(v);
    }
  }
  // ---- GEMM2: z2 = hidden @ W2 + b2 ----
  {
    short8 af[4];
#pragma unroll
    for (int s = 0; s < 4; ++s)
      af[s] = *reinterpret_cast<const short8*>(&Hbuf[(w * 16 + l15) * 136 + s * 32 + kgrp * 8]);
    const unsigned short* W2p = Wp + 16384;
#pragma unroll
    for (int tt = 0; tt < 8; ++tt) {
      float bb = b2[tt * 16 + l15];
      acc[tt] = (f32x4){bb, bb, bb, bb};
#pragma unroll
      for (int s = 0; s < 4; ++s) {
        bf16x8 bf = *reinterpret_cast<const bf16x8*>(W2p + ((tt * 4 + s) * 64 + lane) * 8);
        acc[tt] = __builtin_amdgcn_mfma_f32_16x16x32_bf16(
            __builtin_bit_cast(bf16x8, af[s]), bf, acc[tt], 0, 0, 0);
      }
    }
  }
  // ---- epilogue: store z2 + BN stats ----
#pragma unroll
  for (int tt = 0; tt < 8; ++tt) {
    int c = tt * 16 + l15;
    float s = 0.f, q = 0.f;
#pragma unroll
    for (int j = 0; j < 4; ++j) {
      int r = row0 + w * 16 + kgrp * 4 + j;
      if (r < NN) {
        float v = acc[tt][j];
        Z2[(long)r * HD + c] = v;
        s += v; q += v * v;
      }
    }
    atomicAdd(&red[c], s);
    atomicAdd(&red[128 + c], q);
  }
  __syncthreads();
  atomicAdd(&accum[t], red[t]);
}

// ---------------- batchnorm finalize ----------------
__global__ void bn_finalize(const float* __restrict__ accum, const float* __restrict__ gamma,
                            const float* __restrict__ beta, float* __restrict__ ss) {
  const int c = threadIdx.x;  // 128
  const float n = (float)NN;
  float mu  = accum[c] / n;
  float var = accum[128 + c] / n - mu * mu;
  float rstd = rsqrtf(var + 1e-5f);
  float sc = rstd * gamma[c];
  ss[c] = sc;
  ss[128 + c] = beta[c] - mu * sc;
}

// ---------------- pooling with fused BN ----------------
__global__ void pool_kernel(const float* __restrict__ z2, const float* __restrict__ ss,
                            const int* __restrict__ batch,
                            float* __restrict__ smean, float* __restrict__ smax,
                            float* __restrict__ ssum) {
  const int b = blockIdx.x;   // 256
  const int c = threadIdx.x;  // 128
  const float sc = ss[c];
  const float sh = ss[128 + c];
  int lo = 0, hi = NN;
  while (lo < hi) { int mid = (lo + hi) >> 1; if (batch[mid] < b) lo = mid + 1; else hi = mid; }
  const int start = lo;
  hi = NN;
  while (lo < hi) { int mid = (lo + hi) >> 1; if (batch[mid] < b + 1) lo = mid + 1; else hi = mid; }
  const int end = lo;
  float s = 0.0f, m = -INFINITY;
  for (int row = start; row < end; ++row) {
    float v = fmaf(z2[(long)row * HD + c], sc, sh);
    s += v;
    m = fmaxf(m, v);
  }
  const int cnt = end - start;
  ssum[b * HD + c]  = s;
  smean[b * HD + c] = s / fmaxf((float)cnt, 1.0f);
  smax[b * HD + c]  = (cnt > 0) ? m : 0.0f;
}

// ---------------- order encoder + score head ----------------
__global__ void head_kernel(const float* __restrict__ orders,
                            const float* __restrict__ oW1, const float* __restrict__ ob1,
                            const float* __restrict__ oW2, const float* __restrict__ ob2,
                            const float* __restrict__ sW1, const float* __restrict__ sb1,
                            const float* __restrict__ sW2, const float* __restrict__ sb2,
                            const float* __restrict__ sW3, const float* __restrict__ sb3,
                            const float* __restrict__ smean, const float* __restrict__ smax,
                            const float* __restrict__ ssum, float* __restrict__ out) {
  __shared__ float t1[128];
  __shared__ float comb[512];
  __shared__ float s1[128];
  __shared__ float s2[64];
  const int bo = blockIdx.x;
  const int b = bo >> 5;
  const int tid = threadIdx.x;  // 128

  {
    float acc = ob1[tid];
    const float* orow = orders + (long)bo * 32;
    for (int k = 0; k < 32; ++k) acc += orow[k] * oW1[k * 128 + tid];
    t1[tid] = fmaxf(acc, 0.0f);
  }
  comb[tid]       = smean[b * HD + tid];
  comb[128 + tid] = smax[b * HD + tid];
  comb[256 + tid] = ssum[b * HD + tid];
  __syncthreads();
  {
    float acc = ob2[tid];
    for (int k = 0; k < 128; ++k) acc += t1[k] * oW2[k * 128 + tid];
    comb[384 + tid] = acc;
  }
  __syncthreads();
  {
    float acc = sb1[tid];
    for (int k = 0; k < 512; ++k) acc += comb[k] * sW1[k * 128 + tid];
    s1[tid] = fmaxf(acc, 0.0f);
  }
  __syncthreads();
  if (tid < 64) {
    float acc = sb2[tid];
    for (int k = 0; k < 128; ++k) acc += s1[k] * sW2[k * 64 + tid];
    s2[tid] = fmaxf(acc, 0.0f);
  }
  __syncthreads();
  if (tid == 0) {
    float acc = sb3[0];
    for (int k = 0; k < 64; ++k) acc += s2[k] * sW3[k];
    out[bo] = acc;
  }
}

extern "C" void kernel_launch(void* const* d_in, const int* in_sizes, int n_in,
                              void* d_out, int out_size, void* d_ws, size_t ws_size,
                              hipStream_t stream) {
  const float* x      = (const float*)d_in[0];
  const int*   ei     = (const int*)d_in[1];
  const float* orders = (const float*)d_in[2];
  const int*   batch  = (const int*)d_in[3];
  const float* gW1    = (const float*)d_in[4];
  const float* gb1    = (const float*)d_in[5];
  const float* gW2    = (const float*)d_in[6];
  const float* gb2    = (const float*)d_in[7];
  const float* gamma  = (const float*)d_in[8];
  const float* beta   = (const float*)d_in[9];
  const float* oW1    = (const float*)d_in[10];
  const float* ob1    = (const float*)d_in[11];
  const float* oW2    = (const float*)d_in[12];
  const float* ob2    = (const float*)d_in[13];
  const float* sW1    = (const float*)d_in[14];
  const float* sb1    = (const float*)d_in[15];
  const float* sW2    = (const float*)d_in[16];
  const float* sb2    = (const float*)d_in[17];
  const float* sW3    = (const float*)d_in[18];
  const float* sb3    = (const float*)d_in[19];
  float* out = (float*)d_out;

  char* ws = (char*)d_ws;
  float* bufA = (float*)ws;                       // z          [NN,128]
  float* bufC = (float*)(ws + NH * 4);            // z2 (pre-BN)[NN,128]
  char* small = ws + 2 * NH * 4;
  float* accum = (float*)small;                   // 256
  float* ssbn  = accum + 256;                     // 256 (scale|shift)
  float* ssum  = ssbn + 256;                      // 256*128
  float* smean = ssum + NB * HD;                  // 256*128
  float* smax  = smean + NB * HD;                 // 256*128
  int* rowptr = (int*)(smax + NB * HD);           // NN
  int* col    = rowptr + NN;                      // NE (also aliased as cnt during CSR build)
  int* cnt    = col;                              // alias: dead before fill writes col
  int* bsum   = col + NE;                         // NBLK_SCAN
  unsigned short* Wp = (unsigned short*)(bsum + NBLK_SCAN);  // 3*2*16384 bf16

  // ---- CSR build (by dst), once ----
  hipMemsetAsync(cnt, 0, NN * sizeof(int), stream);
  hist_kernel<<<(NE + 255) / 256, 256, 0, stream>>>(ei, cnt);
  bsum_kernel<<<NBLK_SCAN, 256, 0, stream>>>(cnt, bsum);
  bscan_kernel<<<1, 1024, 0, stream>>>(bsum);
  local_scan_kernel<<<NBLK_SCAN, 256, 0, stream>>>(cnt, bsum, rowptr);
  fill_kernel<<<(NE + 255) / 256, 256, 0, stream>>>(ei, rowptr, col);

  // ---- pack weights to bf16 MFMA fragments, once ----
  pack_w_kernel<<<48, 256, 0, stream>>>(gW1, gW2, Wp);

  const int GATHER_GRID = NN / 4;
  const int LAYER_GRID = (NN + 63) / 64;
  for (int l = 0; l < 3; ++l) {
    if (l == 0)
      gather_kernel<false, false><<<GATHER_GRID, 256, 0, stream>>>(x, rowptr, col, ssbn, bufA);
    else
      gather_kernel<true, true><<<GATHER_GRID, 256, 0, stream>>>(bufC, rowptr, col, ssbn, bufA);
    hipMemsetAsync(accum, 0, 256 * sizeof(float), stream);
    fused_layer<<<LAYER_GRID, 256, 0, stream>>>(
        bufA, Wp + (long)l * 32768, gb1 + l * 128, gb2 + l * 128, bufC, accum);
    bn_finalize<<<1, 128, 0, stream>>>(accum, gamma + l * 128, beta + l * 128, ssbn);
  }

  pool_kernel<<<NB, 128, 0, stream>>>(bufC, ssbn, batch, smean, smax, ssum);
  head_kernel<<<NB * NO, 128, 0, stream>>>(orders, oW1, ob1, oW2, ob2,
                                           sW1, sb1, sW2, sb2, sW3, sb3,
                                           smean, smax, ssum, out);
}

// Round 6
// 845.119 us; speedup vs baseline: 11.4148x; 1.2136x over previous
//
#include <hip/hip_runtime.h>

static constexpr int NN = 100000;   // nodes
static constexpr int NE = 1600000;  // edges
static constexpr int NB = 256;     // graphs
static constexpr int NO = 32;      // orders per graph
static constexpr int HD = 128;     // hidden dim
static constexpr long NH = (long)NN * HD;
static constexpr int NBLK_SCAN = (NN + 255) / 256;  // 391

typedef _Float16 f16x8 __attribute__((ext_vector_type(8)));
typedef _Float16 f16x2 __attribute__((ext_vector_type(2)));
typedef float f32x4 __attribute__((ext_vector_type(4)));

// ---------------- CSR build ----------------
__global__ void hist_kernel(const int* __restrict__ ei, int* __restrict__ cnt) {
  int e = blockIdx.x * blockDim.x + threadIdx.x;
  if (e >= NE) return;
  atomicAdd(&cnt[ei[NE + e]], 1);
}

__global__ void bsum_kernel(const int* __restrict__ cnt, int* __restrict__ bsum) {
  __shared__ int sh[256];
  int gid = blockIdx.x * 256 + threadIdx.x;
  sh[threadIdx.x] = (gid < NN) ? cnt[gid] : 0;
  __syncthreads();
  for (int off = 128; off > 0; off >>= 1) {
    if (threadIdx.x < off) sh[threadIdx.x] += sh[threadIdx.x + off];
    __syncthreads();
  }
  if (threadIdx.x == 0) bsum[blockIdx.x] = sh[0];
}

__global__ void bscan_kernel(int* __restrict__ bsum) {
  __shared__ int part[1024];
  int t = threadIdx.x;
  int v = (t < NBLK_SCAN) ? bsum[t] : 0;
  part[t] = v;
  __syncthreads();
  for (int off = 1; off < 1024; off <<= 1) {
    int u = (t >= off) ? part[t - off] : 0;
    __syncthreads();
    part[t] += u;
    __syncthreads();
  }
  if (t < NBLK_SCAN) bsum[t] = part[t] - v;  // exclusive
}

__global__ void local_scan_kernel(const int* __restrict__ cnt, const int* __restrict__ bsum,
                                  int* __restrict__ rowptr) {
  __shared__ int part[256];
  int t = threadIdx.x;
  int gid = blockIdx.x * 256 + t;
  int v = (gid < NN) ? cnt[gid] : 0;
  part[t] = v;
  __syncthreads();
  for (int off = 1; off < 256; off <<= 1) {
    int u = (t >= off) ? part[t - off] : 0;
    __syncthreads();
    part[t] += u;
    __syncthreads();
  }
  if (gid < NN) rowptr[gid] = part[t] - v + bsum[blockIdx.x];
}

// after this kernel rowptr[n] == end offset of node n
__global__ void fill_kernel(const int* __restrict__ ei, int* __restrict__ rowptr,
                            int* __restrict__ col) {
  int e = blockIdx.x * blockDim.x + threadIdx.x;
  if (e >= NE) return;
  int s = ei[e];
  int d = ei[NE + e];
  int pos = atomicAdd(&rowptr[d], 1);
  col[pos] = s;
}

// ---------------- x fp32 -> fp16, once ----------------
__global__ void f32to16_kernel(const float* __restrict__ in, _Float16* __restrict__ out) {
  long i = (long)(blockIdx.x * 256 + threadIdx.x) * 8;
  if (i >= NH) return;
  float4 a = *reinterpret_cast<const float4*>(in + i);
  float4 b = *reinterpret_cast<const float4*>(in + i + 4);
  f16x8 v;
  v[0] = (_Float16)a.x; v[1] = (_Float16)a.y; v[2] = (_Float16)a.z; v[3] = (_Float16)a.w;
  v[4] = (_Float16)b.x; v[5] = (_Float16)b.y; v[6] = (_Float16)b.z; v[7] = (_Float16)b.w;
  *reinterpret_cast<f16x8*>(out + i) = v;
}

// ---------------- weight packing: fp32 W[128][128] -> fp16 MFMA B-fragments ----------------
// lane holds W[s*32+(lane>>4)*8+j][t*16+(lane&15)]
__global__ void pack_w_kernel(const float* __restrict__ gW1, const float* __restrict__ gW2,
                              _Float16* __restrict__ Wp) {
  int tid = blockIdx.x * blockDim.x + threadIdx.x;  // 3*2*8*4*64 = 12288
  if (tid >= 12288) return;
  int lane = tid & 63;
  int s = (tid >> 6) & 3;
  int t = (tid >> 8) & 7;
  int which = (tid >> 11) & 1;
  int layer = tid >> 12;
  const float* W = (which ? gW2 : gW1) + (long)layer * 128 * 128;
  _Float16* dst = Wp + (long)tid * 8;
  int kbase = s * 32 + ((lane >> 4) << 3);
  int n = t * 16 + (lane & 15);
#pragma unroll
  for (int j = 0; j < 8; ++j) dst[j] = (_Float16)W[(kbase + j) * 128 + n];
}

// ---------------- gather: z[n] = f(hin[n]) + sum_j f(hin[col[j]]) ----------------
// f = identity (layer 0) or BN(+ReLU) of previous layer (params derived from accum)
template <bool BN, bool RELU>
__global__ void gather_kernel(const _Float16* __restrict__ hin, const int* __restrict__ rowptr,
                              const int* __restrict__ col, const float* __restrict__ accum,
                              const float* __restrict__ gamma, const float* __restrict__ beta,
                              _Float16* __restrict__ z) {
  const int node = (blockIdx.x * blockDim.x + threadIdx.x) >> 6;
  if (node >= NN) return;
  const int c2 = (threadIdx.x & 63) * 2;
  float scx = 1.f, scy = 1.f, shx = 0.f, shy = 0.f;
  if (BN) {
    const float n = (float)NN;
    float mu0 = accum[c2] / n, mu1 = accum[c2 + 1] / n;
    float v0 = accum[128 + c2] / n - mu0 * mu0;
    float v1 = accum[128 + c2 + 1] / n - mu1 * mu1;
    scx = rsqrtf(v0 + 1e-5f) * gamma[c2];
    scy = rsqrtf(v1 + 1e-5f) * gamma[c2 + 1];
    shx = beta[c2] - mu0 * scx;
    shy = beta[c2 + 1] - mu1 * scy;
  }
  auto ldh = [&](int n) -> float2 {
    f16x2 h = *reinterpret_cast<const f16x2*>(hin + (long)n * HD + c2);
    float2 v = make_float2((float)h[0], (float)h[1]);
    if (BN) {
      v.x = fmaf(v.x, scx, shx);
      v.y = fmaf(v.y, scy, shy);
      if (RELU) { v.x = fmaxf(v.x, 0.f); v.y = fmaxf(v.y, 0.f); }
    }
    return v;
  };
  const int lo = (node == 0) ? 0 : rowptr[node - 1];
  const int hi = rowptr[node];
  float2 acc = ldh(node);
  int j = lo;
  for (; j + 4 <= hi; j += 4) {
    int s0 = col[j], s1 = col[j + 1], s2 = col[j + 2], s3 = col[j + 3];
    float2 v0 = ldh(s0), v1 = ldh(s1), v2 = ldh(s2), v3 = ldh(s3);
    acc.x += (v0.x + v1.x) + (v2.x + v3.x);
    acc.y += (v0.y + v1.y) + (v2.y + v3.y);
  }
  if (j < hi) {
    int last = hi - 1;
    int s0 = col[j];
    int s1 = col[min(j + 1, last)];
    int s2 = col[min(j + 2, last)];
    int s3 = col[min(j + 3, last)];
    float m1 = (j + 1 < hi) ? 1.f : 0.f;
    float m2 = (j + 2 < hi) ? 1.f : 0.f;
    float m3 = (j + 3 < hi) ? 1.f : 0.f;
    float2 v0 = ldh(s0), v1 = ldh(s1), v2 = ldh(s2), v3 = ldh(s3);
    acc.x += v0.x + m1 * v1.x + m2 * v2.x + m3 * v3.x;
    acc.y += v0.y + m1 * v1.y + m2 * v2.y + m3 * v3.y;
  }
  f16x2 o;
  o[0] = (_Float16)acc.x;
  o[1] = (_Float16)acc.y;
  *reinterpret_cast<f16x2*>(z + (long)node * HD + c2) = o;
}

// ---------------- fused GIN layer: z2 = (ReLU(z@W1+b1))@W2 + b2, BN stats fused ----------------
// 64 rows/block, 4 waves; wave w owns rows [w*16, w*16+16). MFMA 16x16x32 f16.
__global__ void __launch_bounds__(256)
fused_layer(const _Float16* __restrict__ Z, const _Float16* __restrict__ Wp,
            const float* __restrict__ b1, const float* __restrict__ b2,
            _Float16* __restrict__ Z2, float* __restrict__ accum) {
  __shared__ _Float16 Abuf[64 * 136];
  __shared__ _Float16 Hbuf[64 * 136];
  __shared__ float red[256];
  const int t = threadIdx.x;
  const int row0 = blockIdx.x * 64;
  const int lane = t & 63;
  const int w = t >> 6;
  const int l15 = lane & 15;
  const int kgrp = lane >> 4;

  // stage Z (fp16) -> LDS, 16B chunks, row stride 136
  for (int idx = t; idx < 64 * 16; idx += 256) {
    int r = idx >> 4;
    int c8 = (idx & 15) * 8;
    int row = row0 + r;
    f16x8 v = {};
    if (row < NN) v = *reinterpret_cast<const f16x8*>(Z + (long)row * HD + c8);
    *reinterpret_cast<f16x8*>(&Abuf[r * 136 + c8]) = v;
  }
  red[t] = 0.f;
  __syncthreads();

  f32x4 acc[8];
  // ---- GEMM1: hidden = ReLU(A @ W1 + b1) ----
  {
    f16x8 af[4];
#pragma unroll
    for (int s = 0; s < 4; ++s)
      af[s] = *reinterpret_cast<const f16x8*>(&Abuf[(w * 16 + l15) * 136 + s * 32 + kgrp * 8]);
    const _Float16* W1p = Wp;
#pragma unroll
    for (int tt = 0; tt < 8; ++tt) {
      float bb = b1[tt * 16 + l15];
      acc[tt] = (f32x4){bb, bb, bb, bb};
#pragma unroll
      for (int s = 0; s < 4; ++s) {
        f16x8 bf = *reinterpret_cast<const f16x8*>(W1p + ((tt * 4 + s) * 64 + lane) * 8);
        acc[tt] = __builtin_amdgcn_mfma_f32_16x16x32_f16(af[s], bf, acc[tt], 0, 0, 0);
      }
    }
  }
  // hidden -> LDS (wave-local rows; no barrier)
#pragma unroll
  for (int tt = 0; tt < 8; ++tt) {
#pragma unroll
    for (int j = 0; j < 4; ++j) {
      float v = fmaxf(acc[tt][j], 0.f);
      Hbuf[(w * 16 + kgrp * 4 + j) * 136 + tt * 16 + l15] = (_Float16)v;
    }
  }
  // ---- GEMM2: z2 = hidden @ W2 + b2 ----
  {
    f16x8 af[4];
#pragma unroll
    for (int s = 0; s < 4; ++s)
      af[s] = *reinterpret_cast<const f16x8*>(&Hbuf[(w * 16 + l15) * 136 + s * 32 + kgrp * 8]);
    const _Float16* W2p = Wp + 16384;
#pragma unroll
    for (int tt = 0; tt < 8; ++tt) {
      float bb = b2[tt * 16 + l15];
      acc[tt] = (f32x4){bb, bb, bb, bb};
#pragma unroll
      for (int s = 0; s < 4; ++s) {
        f16x8 bf = *reinterpret_cast<const f16x8*>(W2p + ((tt * 4 + s) * 64 + lane) * 8);
        acc[tt] = __builtin_amdgcn_mfma_f32_16x16x32_f16(af[s], bf, acc[tt], 0, 0, 0);
      }
    }
  }
  // ---- epilogue: store z2 (fp16) + BN stats (fp32) ----
#pragma unroll
  for (int tt = 0; tt < 8; ++tt) {
    int c = tt * 16 + l15;
    float s = 0.f, q = 0.f;
#pragma unroll
    for (int j = 0; j < 4; ++j) {
      int r = row0 + w * 16 + kgrp * 4 + j;
      if (r < NN) {
        float v = acc[tt][j];
        Z2[(long)r * HD + c] = (_Float16)v;
        s += v; q += v * v;
      }
    }
    atomicAdd(&red[c], s);
    atomicAdd(&red[128 + c], q);
  }
  __syncthreads();
  atomicAdd(&accum[t], red[t]);
}

// ---------------- pooling with fused BN (params from accum; no relu) ----------------
__global__ void pool_kernel(const _Float16* __restrict__ z2, const float* __restrict__ accum,
                            const float* __restrict__ gamma, const float* __restrict__ beta,
                            const int* __restrict__ batch,
                            float* __restrict__ smean, float* __restrict__ smax,
                            float* __restrict__ ssum) {
  const int b = blockIdx.x;   // 256
  const int c = threadIdx.x;  // 128
  const float n = (float)NN;
  float mu = accum[c] / n;
  float var = accum[128 + c] / n - mu * mu;
  const float sc = rsqrtf(var + 1e-5f) * gamma[c];
  const float sh = beta[c] - mu * sc;
  int lo = 0, hi = NN;
  while (lo < hi) { int mid = (lo + hi) >> 1; if (batch[mid] < b) lo = mid + 1; else hi = mid; }
  const int start = lo;
  hi = NN;
  while (lo < hi) { int mid = (lo + hi) >> 1; if (batch[mid] < b + 1) lo = mid + 1; else hi = mid; }
  const int end = lo;
  float s = 0.0f, m = -INFINITY;
  for (int row = start; row < end; ++row) {
    float v = fmaf((float)z2[(long)row * HD + c], sc, sh);
    s += v;
    m = fmaxf(m, v);
  }
  const int cnt = end - start;
  ssum[b * HD + c]  = s;
  smean[b * HD + c] = s / fmaxf((float)cnt, 1.0f);
  smax[b * HD + c]  = (cnt > 0) ? m : 0.0f;
}

// ---------------- order encoder + score head ----------------
__global__ void head_kernel(const float* __restrict__ orders,
                            const float* __restrict__ oW1, const float* __restrict__ ob1,
                            const float* __restrict__ oW2, const float* __restrict__ ob2,
                            const float* __restrict__ sW1, const float* __restrict__ sb1,
                            const float* __restrict__ sW2, const float* __restrict__ sb2,
                            const float* __restrict__ sW3, const float* __restrict__ sb3,
                            const float* __restrict__ smean, const float* __restrict__ smax,
                            const float* __restrict__ ssum, float* __restrict__ out) {
  __shared__ float t1[128];
  __shared__ float comb[512];
  __shared__ float s1[128];
  __shared__ float s2[64];
  const int bo = blockIdx.x;
  const int b = bo >> 5;
  const int tid = threadIdx.x;  // 128

  {
    float acc = ob1[tid];
    const float* orow = orders + (long)bo * 32;
    for (int k = 0; k < 32; ++k) acc += orow[k] * oW1[k * 128 + tid];
    t1[tid] = fmaxf(acc, 0.0f);
  }
  comb[tid]       = smean[b * HD + tid];
  comb[128 + tid] = smax[b * HD + tid];
  comb[256 + tid] = ssum[b * HD + tid];
  __syncthreads();
  {
    float acc = ob2[tid];
    for (int k = 0; k < 128; ++k) acc += t1[k] * oW2[k * 128 + tid];
    comb[384 + tid] = acc;
  }
  __syncthreads();
  {
    float acc = sb1[tid];
    for (int k = 0; k < 512; ++k) acc += comb[k] * sW1[k * 128 + tid];
    s1[tid] = fmaxf(acc, 0.0f);
  }
  __syncthreads();
  if (tid < 64) {
    float acc = sb2[tid];
    for (int k = 0; k < 128; ++k) acc += s1[k] * sW2[k * 64 + tid];
    s2[tid] = fmaxf(acc, 0.0f);
  }
  __syncthreads();
  if (tid == 0) {
    float acc = sb3[0];
    for (int k = 0; k < 64; ++k) acc += s2[k] * sW3[k];
    out[bo] = acc;
  }
}

extern "C" void kernel_launch(void* const* d_in, const int* in_sizes, int n_in,
                              void* d_out, int out_size, void* d_ws, size_t ws_size,
                              hipStream_t stream) {
  const float* x      = (const float*)d_in[0];
  const int*   ei     = (const int*)d_in[1];
  const float* orders = (const float*)d_in[2];
  const int*   batch  = (const int*)d_in[3];
  const float* gW1    = (const float*)d_in[4];
  const float* gb1    = (const float*)d_in[5];
  const float* gW2    = (const float*)d_in[6];
  const float* gb2    = (const float*)d_in[7];
  const float* gamma  = (const float*)d_in[8];
  const float* beta   = (const float*)d_in[9];
  const float* oW1    = (const float*)d_in[10];
  const float* ob1    = (const float*)d_in[11];
  const float* oW2    = (const float*)d_in[12];
  const float* ob2    = (const float*)d_in[13];
  const float* sW1    = (const float*)d_in[14];
  const float* sb1    = (const float*)d_in[15];
  const float* sW2    = (const float*)d_in[16];
  const float* sb2    = (const float*)d_in[17];
  const float* sW3    = (const float*)d_in[18];
  const float* sb3    = (const float*)d_in[19];
  float* out = (float*)d_out;

  char* ws = (char*)d_ws;
  _Float16* xh    = (_Float16*)ws;                // x fp16        [NN,128]
  _Float16* bufAh = xh + NH;                      // z fp16        [NN,128]
  _Float16* bufCh = bufAh + NH;                   // z2 fp16       [NN,128]
  float* accum = (float*)(bufCh + NH);            // 256
  float* ssum  = accum + 256;                     // 256*128
  float* smean = ssum + NB * HD;                  // 256*128
  float* smax  = smean + NB * HD;                 // 256*128
  int* rowptr = (int*)(smax + NB * HD);           // NN
  int* col    = rowptr + NN;                      // NE (aliased as cnt during CSR build)
  int* cnt    = col;                              // alias: dead before fill writes col
  int* bsum   = col + NE;                         // NBLK_SCAN
  _Float16* Wp = (_Float16*)(bsum + NBLK_SCAN);   // 3*2*16384 fp16

  // ---- CSR build (by dst), once ----
  hipMemsetAsync(cnt, 0, NN * sizeof(int), stream);
  hist_kernel<<<(NE + 255) / 256, 256, 0, stream>>>(ei, cnt);
  bsum_kernel<<<NBLK_SCAN, 256, 0, stream>>>(cnt, bsum);
  bscan_kernel<<<1, 1024, 0, stream>>>(bsum);
  local_scan_kernel<<<NBLK_SCAN, 256, 0, stream>>>(cnt, bsum, rowptr);
  fill_kernel<<<(NE + 255) / 256, 256, 0, stream>>>(ei, rowptr, col);

  // ---- pack weights + convert x, once ----
  pack_w_kernel<<<48, 256, 0, stream>>>(gW1, gW2, Wp);
  f32to16_kernel<<<(int)(NH / 8 + 255) / 256, 256, 0, stream>>>(x, xh);

  const int GATHER_GRID = NN / 4;
  const int LAYER_GRID = (NN + 63) / 64;
  for (int l = 0; l < 3; ++l) {
    if (l == 0)
      gather_kernel<false, false><<<GATHER_GRID, 256, 0, stream>>>(
          xh, rowptr, col, accum, gamma, beta, bufAh);
    else
      gather_kernel<true, true><<<GATHER_GRID, 256, 0, stream>>>(
          bufCh, rowptr, col, accum, gamma + (l - 1) * 128, beta + (l - 1) * 128, bufAh);
    hipMemsetAsync(accum, 0, 256 * sizeof(float), stream);
    fused_layer<<<LAYER_GRID, 256, 0, stream>>>(
        bufAh, Wp + (long)l * 32768, gb1 + l * 128, gb2 + l * 128, bufCh, accum);
  }

  pool_kernel<<<NB, 128, 0, stream>>>(bufCh, accum, gamma + 2 * 128, beta + 2 * 128,
                                      batch, smean, smax, ssum);
  head_kernel<<<NB * NO, 128, 0, stream>>>(orders, oW1, ob1, oW2, ob2,
                                           sW1, sb1, sW2, sb2, sW3, sb3,
                                           smean, smax, ssum, out);
}

// Round 7
// 723.671 us; speedup vs baseline: 13.3304x; 1.1678x over previous
//
#include <hip/hip_runtime.h>

static constexpr int NN = 100000;   // nodes
static constexpr int NE = 1600000;  // edges
static constexpr int NB = 256;     // graphs
static constexpr int NO = 32;      // orders per graph
static constexpr int HD = 128;     // hidden dim
static constexpr long NH = (long)NN * HD;

static constexpr int BSHIFT = 9;                 // bucket = dst >> 9
static constexpr int BSIZE = 1 << BSHIFT;        // 512 nodes per bucket
static constexpr int NBUCK = 256;                // 196 used, rest empty
static constexpr int CHUNK = 16384;
static constexpr int NCHUNK = (NE + CHUNK - 1) / CHUNK;  // 98

typedef _Float16 f16x8 __attribute__((ext_vector_type(8)));
typedef _Float16 f16x2 __attribute__((ext_vector_type(2)));
typedef float f32x4 __attribute__((ext_vector_type(4)));

// ================= CSR build: two-level locality-aware counting sort =================
// pass 1: coarse histogram (dst>>9) via LDS, one global atomic per (block,bucket)
__global__ void bucket_count(const int* __restrict__ ei, int* __restrict__ bucketTotal) {
  __shared__ int cnt[NBUCK];
  const int t = threadIdx.x;  // 256
  cnt[t] = 0;
  __syncthreads();
  long start = (long)blockIdx.x * CHUNK;
  long end = min((long)NE, start + CHUNK);
  for (long e = start + t; e < end; e += 256)
    atomicAdd(&cnt[ei[NE + e] >> BSHIFT], 1);
  __syncthreads();
  if (cnt[t]) atomicAdd(&bucketTotal[t], cnt[t]);
}

// exclusive scan of 256 bucket totals -> bases + cursors
__global__ void bucket_scan(const int* __restrict__ bucketTotal, int* __restrict__ bucketBase,
                            int* __restrict__ cursor) {
  __shared__ int part[NBUCK];
  const int t = threadIdx.x;  // 256
  int v = bucketTotal[t];
  part[t] = v;
  __syncthreads();
  for (int off = 1; off < NBUCK; off <<= 1) {
    int u = (t >= off) ? part[t - off] : 0;
    __syncthreads();
    part[t] += u;
    __syncthreads();
  }
  int base = part[t] - v;
  bucketBase[t] = base;
  cursor[t] = base;
  if (t == NBUCK - 1) bucketBase[NBUCK] = part[t];
}

// pass 2: bin edges into bucket runs; packed record (src<<9)|(dst&511), 4B
__global__ void bucket_scatter(const int* __restrict__ ei, int* __restrict__ cursor,
                               unsigned int* __restrict__ binned) {
  __shared__ int cnt[NBUCK];
  __shared__ int runbase[NBUCK];
  const int t = threadIdx.x;  // 256
  cnt[t] = 0;
  __syncthreads();
  long start = (long)blockIdx.x * CHUNK;
  long end = min((long)NE, start + CHUNK);
  for (long e = start + t; e < end; e += 256)
    atomicAdd(&cnt[ei[NE + e] >> BSHIFT], 1);
  __syncthreads();
  int c = cnt[t];
  runbase[t] = c ? atomicAdd(&cursor[t], c) : 0;
  cnt[t] = 0;  // reuse as local run cursor
  __syncthreads();
  for (long e = start + t; e < end; e += 256) {
    int d = ei[NE + e], s = ei[e];
    int b = d >> BSHIFT;
    int pos = runbase[b] + atomicAdd(&cnt[b], 1);
    binned[pos] = ((unsigned int)s << BSHIFT) | (unsigned int)(d & (BSIZE - 1));
  }
}

// pass 3: per-bucket fine counting sort -> rowptr (ends) + col
__global__ void bucket_csr(const unsigned int* __restrict__ binned,
                           const int* __restrict__ bucketBase,
                           int* __restrict__ rowptr, int* __restrict__ col) {
  __shared__ int cnt[BSIZE];
  __shared__ int excl[BSIZE];
  __shared__ int cur[BSIZE];
  __shared__ int part[256];
  const int b = blockIdx.x;
  const int t = threadIdx.x;  // 256
  const int lo = bucketBase[b], hi = bucketBase[b + 1];
  cnt[t] = 0; cnt[t + 256] = 0;
  __syncthreads();
  for (int i = lo + t; i < hi; i += 256)
    atomicAdd(&cnt[binned[i] & (BSIZE - 1)], 1);
  __syncthreads();
  // exclusive scan of 512 counters with 256 threads
  int a0 = cnt[2 * t], a1 = cnt[2 * t + 1];
  int s = a0 + a1;
  part[t] = s;
  __syncthreads();
  for (int off = 1; off < 256; off <<= 1) {
    int u = (t >= off) ? part[t - off] : 0;
    __syncthreads();
    part[t] += u;
    __syncthreads();
  }
  int ebase = part[t] - s;
  excl[2 * t] = ebase;
  excl[2 * t + 1] = ebase + a0;
  __syncthreads();
  const int node0 = b * BSIZE;
  for (int i = t; i < BSIZE; i += 256) {
    int node = node0 + i;
    if (node < NN) rowptr[node] = lo + excl[i] + cnt[i];  // inclusive end
    cur[i] = lo + excl[i];
  }
  __syncthreads();
  for (int i = lo + t; i < hi; i += 256) {
    unsigned int v = binned[i];
    int pos = atomicAdd(&cur[v & (BSIZE - 1)], 1);
    col[pos] = (int)(v >> BSHIFT);
  }
}

// ---------------- x fp32 -> fp16, once ----------------
__global__ void f32to16_kernel(const float* __restrict__ in, _Float16* __restrict__ out) {
  long i = (long)(blockIdx.x * 256 + threadIdx.x) * 8;
  if (i >= NH) return;
  float4 a = *reinterpret_cast<const float4*>(in + i);
  float4 b = *reinterpret_cast<const float4*>(in + i + 4);
  f16x8 v;
  v[0] = (_Float16)a.x; v[1] = (_Float16)a.y; v[2] = (_Float16)a.z; v[3] = (_Float16)a.w;
  v[4] = (_Float16)b.x; v[5] = (_Float16)b.y; v[6] = (_Float16)b.z; v[7] = (_Float16)b.w;
  *reinterpret_cast<f16x8*>(out + i) = v;
}

// ---------------- weight packing: fp32 W[128][128] -> fp16 MFMA B-fragments ----------------
// lane holds W[s*32+(lane>>4)*8+j][t*16+(lane&15)]
__global__ void pack_w_kernel(const float* __restrict__ gW1, const float* __restrict__ gW2,
                              _Float16* __restrict__ Wp) {
  int tid = blockIdx.x * blockDim.x + threadIdx.x;  // 3*2*8*4*64 = 12288
  if (tid >= 12288) return;
  int lane = tid & 63;
  int s = (tid >> 6) & 3;
  int t = (tid >> 8) & 7;
  int which = (tid >> 11) & 1;
  int layer = tid >> 12;
  const float* W = (which ? gW2 : gW1) + (long)layer * 128 * 128;
  _Float16* dst = Wp + (long)tid * 8;
  int kbase = s * 32 + ((lane >> 4) << 3);
  int n = t * 16 + (lane & 15);
#pragma unroll
  for (int j = 0; j < 8; ++j) dst[j] = (_Float16)W[(kbase + j) * 128 + n];
}

// ---------------- gather: z[n] = f(hin[n]) + sum_j f(hin[col[j]]) ----------------
// f = identity (layer 0) or BN(+ReLU) of previous layer (params derived from accum)
template <bool BN, bool RELU>
__global__ void gather_kernel(const _Float16* __restrict__ hin, const int* __restrict__ rowptr,
                              const int* __restrict__ col, const float* __restrict__ accum,
                              const float* __restrict__ gamma, const float* __restrict__ beta,
                              _Float16* __restrict__ z) {
  const int node = (blockIdx.x * blockDim.x + threadIdx.x) >> 6;
  if (node >= NN) return;
  const int c2 = (threadIdx.x & 63) * 2;
  float scx = 1.f, scy = 1.f, shx = 0.f, shy = 0.f;
  if (BN) {
    const float n = (float)NN;
    float mu0 = accum[c2] / n, mu1 = accum[c2 + 1] / n;
    float v0 = accum[128 + c2] / n - mu0 * mu0;
    float v1 = accum[128 + c2 + 1] / n - mu1 * mu1;
    scx = rsqrtf(v0 + 1e-5f) * gamma[c2];
    scy = rsqrtf(v1 + 1e-5f) * gamma[c2 + 1];
    shx = beta[c2] - mu0 * scx;
    shy = beta[c2 + 1] - mu1 * scy;
  }
  auto ldh = [&](int n) -> float2 {
    f16x2 h = *reinterpret_cast<const f16x2*>(hin + (long)n * HD + c2);
    float2 v = make_float2((float)h[0], (float)h[1]);
    if (BN) {
      v.x = fmaf(v.x, scx, shx);
      v.y = fmaf(v.y, scy, shy);
      if (RELU) { v.x = fmaxf(v.x, 0.f); v.y = fmaxf(v.y, 0.f); }
    }
    return v;
  };
  const int lo = (node == 0) ? 0 : rowptr[node - 1];
  const int hi = rowptr[node];
  float2 acc = ldh(node);
  int j = lo;
  for (; j + 4 <= hi; j += 4) {
    int s0 = col[j], s1 = col[j + 1], s2 = col[j + 2], s3 = col[j + 3];
    float2 v0 = ldh(s0), v1 = ldh(s1), v2 = ldh(s2), v3 = ldh(s3);
    acc.x += (v0.x + v1.x) + (v2.x + v3.x);
    acc.y += (v0.y + v1.y) + (v2.y + v3.y);
  }
  if (j < hi) {
    int last = hi - 1;
    int s0 = col[j];
    int s1 = col[min(j + 1, last)];
    int s2 = col[min(j + 2, last)];
    int s3 = col[min(j + 3, last)];
    float m1 = (j + 1 < hi) ? 1.f : 0.f;
    float m2 = (j + 2 < hi) ? 1.f : 0.f;
    float m3 = (j + 3 < hi) ? 1.f : 0.f;
    float2 v0 = ldh(s0), v1 = ldh(s1), v2 = ldh(s2), v3 = ldh(s3);
    acc.x += v0.x + m1 * v1.x + m2 * v2.x + m3 * v3.x;
    acc.y += v0.y + m1 * v1.y + m2 * v2.y + m3 * v3.y;
  }
  f16x2 o;
  o[0] = (_Float16)acc.x;
  o[1] = (_Float16)acc.y;
  *reinterpret_cast<f16x2*>(z + (long)node * HD + c2) = o;
}

// ---------------- fused GIN layer: z2 = (ReLU(z@W1+b1))@W2 + b2, BN stats fused ----------------
// 64 rows/block, 4 waves; wave w owns rows [w*16, w*16+16). MFMA 16x16x32 f16.
__global__ void __launch_bounds__(256)
fused_layer(const _Float16* __restrict__ Z, const _Float16* __restrict__ Wp,
            const float* __restrict__ b1, const float* __restrict__ b2,
            _Float16* __restrict__ Z2, float* __restrict__ accum) {
  __shared__ _Float16 Abuf[64 * 136];
  __shared__ _Float16 Hbuf[64 * 136];
  __shared__ float red[256];
  const int t = threadIdx.x;
  const int row0 = blockIdx.x * 64;
  const int lane = t & 63;
  const int w = t >> 6;
  const int l15 = lane & 15;
  const int kgrp = lane >> 4;

  for (int idx = t; idx < 64 * 16; idx += 256) {
    int r = idx >> 4;
    int c8 = (idx & 15) * 8;
    int row = row0 + r;
    f16x8 v = {};
    if (row < NN) v = *reinterpret_cast<const f16x8*>(Z + (long)row * HD + c8);
    *reinterpret_cast<f16x8*>(&Abuf[r * 136 + c8]) = v;
  }
  red[t] = 0.f;
  __syncthreads();

  f32x4 acc[8];
  // ---- GEMM1: hidden = ReLU(A @ W1 + b1) ----
  {
    f16x8 af[4];
#pragma unroll
    for (int s = 0; s < 4; ++s)
      af[s] = *reinterpret_cast<const f16x8*>(&Abuf[(w * 16 + l15) * 136 + s * 32 + kgrp * 8]);
    const _Float16* W1p = Wp;
#pragma unroll
    for (int tt = 0; tt < 8; ++tt) {
      float bb = b1[tt * 16 + l15];
      acc[tt] = (f32x4){bb, bb, bb, bb};
#pragma unroll
      for (int s = 0; s < 4; ++s) {
        f16x8 bf = *reinterpret_cast<const f16x8*>(W1p + ((tt * 4 + s) * 64 + lane) * 8);
        acc[tt] = __builtin_amdgcn_mfma_f32_16x16x32_f16(af[s], bf, acc[tt], 0, 0, 0);
      }
    }
  }
  // hidden -> LDS (wave-local rows; no barrier)
#pragma unroll
  for (int tt = 0; tt < 8; ++tt) {
#pragma unroll
    for (int j = 0; j < 4; ++j) {
      float v = fmaxf(acc[tt][j], 0.f);
      Hbuf[(w * 16 + kgrp * 4 + j) * 136 + tt * 16 + l15] = (_Float16)v;
    }
  }
  // ---- GEMM2: z2 = hidden @ W2 + b2 ----
  {
    f16x8 af[4];
#pragma unroll
    for (int s = 0; s < 4; ++s)
      af[s] = *reinterpret_cast<const f16x8*>(&Hbuf[(w * 16 + l15) * 136 + s * 32 + kgrp * 8]);
    const _Float16* W2p = Wp + 16384;
#pragma unroll
    for (int tt = 0; tt < 8; ++tt) {
      float bb = b2[tt * 16 + l15];
      acc[tt] = (f32x4){bb, bb, bb, bb};
#pragma unroll
      for (int s = 0; s < 4; ++s) {
        f16x8 bf = *reinterpret_cast<const f16x8*>(W2p + ((tt * 4 + s) * 64 + lane) * 8);
        acc[tt] = __builtin_amdgcn_mfma_f32_16x16x32_f16(af[s], bf, acc[tt], 0, 0, 0);
      }
    }
  }
  // ---- epilogue: store z2 (fp16) + BN stats (fp32) ----
#pragma unroll
  for (int tt = 0; tt < 8; ++tt) {
    int c = tt * 16 + l15;
    float s = 0.f, q = 0.f;
#pragma unroll
    for (int j = 0; j < 4; ++j) {
      int r = row0 + w * 16 + kgrp * 4 + j;
      if (r < NN) {
        float v = acc[tt][j];
        Z2[(long)r * HD + c] = (_Float16)v;
        s += v; q += v * v;
      }
    }
    atomicAdd(&red[c], s);
    atomicAdd(&red[128 + c], q);
  }
  __syncthreads();
  atomicAdd(&accum[t], red[t]);
}

// ---------------- pooling with fused BN (params from accum; no relu) ----------------
__global__ void pool_kernel(const _Float16* __restrict__ z2, const float* __restrict__ accum,
                            const float* __restrict__ gamma, const float* __restrict__ beta,
                            const int* __restrict__ batch,
                            float* __restrict__ smean, float* __restrict__ smax,
                            float* __restrict__ ssum) {
  const int b = blockIdx.x;   // 256
  const int c = threadIdx.x;  // 128
  const float n = (float)NN;
  float mu = accum[c] / n;
  float var = accum[128 + c] / n - mu * mu;
  const float sc = rsqrtf(var + 1e-5f) * gamma[c];
  const float sh = beta[c] - mu * sc;
  int lo = 0, hi = NN;
  while (lo < hi) { int mid = (lo + hi) >> 1; if (batch[mid] < b) lo = mid + 1; else hi = mid; }
  const int start = lo;
  hi = NN;
  while (lo < hi) { int mid = (lo + hi) >> 1; if (batch[mid] < b + 1) lo = mid + 1; else hi = mid; }
  const int end = lo;
  float s = 0.0f, m = -INFINITY;
  for (int row = start; row < end; ++row) {
    float v = fmaf((float)z2[(long)row * HD + c], sc, sh);
    s += v;
    m = fmaxf(m, v);
  }
  const int cnt = end - start;
  ssum[b * HD + c]  = s;
  smean[b * HD + c] = s / fmaxf((float)cnt, 1.0f);
  smax[b * HD + c]  = (cnt > 0) ? m : 0.0f;
}

// ---------------- order encoder + score head ----------------
__global__ void head_kernel(const float* __restrict__ orders,
                            const float* __restrict__ oW1, const float* __restrict__ ob1,
                            const float* __restrict__ oW2, const float* __restrict__ ob2,
                            const float* __restrict__ sW1, const float* __restrict__ sb1,
                            const float* __restrict__ sW2, const float* __restrict__ sb2,
                            const float* __restrict__ sW3, const float* __restrict__ sb3,
                            const float* __restrict__ smean, const float* __restrict__ smax,
                            const float* __restrict__ ssum, float* __restrict__ out) {
  __shared__ float t1[128];
  __shared__ float comb[512];
  __shared__ float s1[128];
  __shared__ float s2[64];
  const int bo = blockIdx.x;
  const int b = bo >> 5;
  const int tid = threadIdx.x;  // 128

  {
    float acc = ob1[tid];
    const float* orow = orders + (long)bo * 32;
    for (int k = 0; k < 32; ++k) acc += orow[k] * oW1[k * 128 + tid];
    t1[tid] = fmaxf(acc, 0.0f);
  }
  comb[tid]       = smean[b * HD + tid];
  comb[128 + tid] = smax[b * HD + tid];
  comb[256 + tid] = ssum[b * HD + tid];
  __syncthreads();
  {
    float acc = ob2[tid];
    for (int k = 0; k < 128; ++k) acc += t1[k] * oW2[k * 128 + tid];
    comb[384 + tid] = acc;
  }
  __syncthreads();
  {
    float acc = sb1[tid];
    for (int k = 0; k < 512; ++k) acc += comb[k] * sW1[k * 128 + tid];
    s1[tid] = fmaxf(acc, 0.0f);
  }
  __syncthreads();
  if (tid < 64) {
    float acc = sb2[tid];
    for (int k = 0; k < 128; ++k) acc += s1[k] * sW2[k * 64 + tid];
    s2[tid] = fmaxf(acc, 0.0f);
  }
  __syncthreads();
  if (tid == 0) {
    float acc = sb3[0];
    for (int k = 0; k < 64; ++k) acc += s2[k] * sW3[k];
    out[bo] = acc;
  }
}

extern "C" void kernel_launch(void* const* d_in, const int* in_sizes, int n_in,
                              void* d_out, int out_size, void* d_ws, size_t ws_size,
                              hipStream_t stream) {
  const float* x      = (const float*)d_in[0];
  const int*   ei     = (const int*)d_in[1];
  const float* orders = (const float*)d_in[2];
  const int*   batch  = (const int*)d_in[3];
  const float* gW1    = (const float*)d_in[4];
  const float* gb1    = (const float*)d_in[5];
  const float* gW2    = (const float*)d_in[6];
  const float* gb2    = (const float*)d_in[7];
  const float* gamma  = (const float*)d_in[8];
  const float* beta   = (const float*)d_in[9];
  const float* oW1    = (const float*)d_in[10];
  const float* ob1    = (const float*)d_in[11];
  const float* oW2    = (const float*)d_in[12];
  const float* ob2    = (const float*)d_in[13];
  const float* sW1    = (const float*)d_in[14];
  const float* sb1    = (const float*)d_in[15];
  const float* sW2    = (const float*)d_in[16];
  const float* sb2    = (const float*)d_in[17];
  const float* sW3    = (const float*)d_in[18];
  const float* sb3    = (const float*)d_in[19];
  float* out = (float*)d_out;

  char* ws = (char*)d_ws;
  _Float16* xh    = (_Float16*)ws;                // x fp16        [NN,128]
  _Float16* bufAh = xh + NH;                      // z fp16        [NN,128]
  _Float16* bufCh = bufAh + NH;                   // z2 fp16       [NN,128]
  float* accum = (float*)(bufCh + NH);            // 256
  float* ssum  = accum + 256;                     // 256*128
  float* smean = ssum + NB * HD;                  // 256*128
  float* smax  = smean + NB * HD;                 // 256*128
  int* rowptr = (int*)(smax + NB * HD);           // NN
  int* col    = rowptr + NN;                      // NE
  unsigned int* binned = (unsigned int*)(col + NE);  // NE
  int* bucketTotal = (int*)(binned + NE);         // 256
  int* bucketBase  = bucketTotal + NBUCK;         // 257
  int* cursor      = bucketBase + NBUCK + 1;      // 256
  _Float16* Wp = (_Float16*)(cursor + NBUCK);     // 3*2*16384 fp16

  // ---- CSR build (by dst): two-level locality-aware counting sort ----
  hipMemsetAsync(bucketTotal, 0, NBUCK * sizeof(int), stream);
  bucket_count<<<NCHUNK, 256, 0, stream>>>(ei, bucketTotal);
  bucket_scan<<<1, NBUCK, 0, stream>>>(bucketTotal, bucketBase, cursor);
  bucket_scatter<<<NCHUNK, 256, 0, stream>>>(ei, cursor, binned);
  bucket_csr<<<NBUCK, 256, 0, stream>>>(binned, bucketBase, rowptr, col);

  // ---- pack weights + convert x, once ----
  pack_w_kernel<<<48, 256, 0, stream>>>(gW1, gW2, Wp);
  f32to16_kernel<<<(int)(NH / 8 + 255) / 256, 256, 0, stream>>>(x, xh);

  const int GATHER_GRID = NN / 4;
  const int LAYER_GRID = (NN + 63) / 64;
  for (int l = 0; l < 3; ++l) {
    if (l == 0)
      gather_kernel<false, false><<<GATHER_GRID, 256, 0, stream>>>(
          xh, rowptr, col, accum, gamma, beta, bufAh);
    else
      gather_kernel<true, true><<<GATHER_GRID, 256, 0, stream>>>(
          bufCh, rowptr, col, accum, gamma + (l - 1) * 128, beta + (l - 1) * 128, bufAh);
    hipMemsetAsync(accum, 0, 256 * sizeof(float), stream);
    fused_layer<<<LAYER_GRID, 256, 0, stream>>>(
        bufAh, Wp + (long)l * 32768, gb1 + l * 128, gb2 + l * 128, bufCh, accum);
  }

  pool_kernel<<<NB, 128, 0, stream>>>(bufCh, accum, gamma + 2 * 128, beta + 2 * 128,
                                      batch, smean, smax, ssum);
  head_kernel<<<NB * NO, 128, 0, stream>>>(orders, oW1, ob1, oW2, ob2,
                                           sW1, sb1, sW2, sb2, sW3, sb3,
                                           smean, smax, ssum, out);
}

// Round 8
// 645.461 us; speedup vs baseline: 14.9456x; 1.1212x over previous
//
#include <hip/hip_runtime.h>

static constexpr int NN = 100000;   // nodes
static constexpr int NE = 1600000;  // edges
static constexpr int NB = 256;     // graphs
static constexpr int NO = 32;      // orders per graph
static constexpr int HD = 128;     // hidden dim
static constexpr long NH = (long)NN * HD;

static constexpr int BSHIFT = 9;                 // bucket = dst >> 9
static constexpr int BSIZE = 1 << BSHIFT;        // 512 nodes per bucket
static constexpr int NBUCK = 256;                // 196 used, rest empty
static constexpr int CHUNK = 16384;
static constexpr int NCHUNK = (NE + CHUNK - 1) / CHUNK;  // 98
static constexpr int POOL_ROWS = 64;
static constexpr int POOL_GRID = (NN + POOL_ROWS - 1) / POOL_ROWS;  // 1563

typedef _Float16 f16x8 __attribute__((ext_vector_type(8)));
typedef _Float16 f16x2 __attribute__((ext_vector_type(2)));
typedef float f32x4 __attribute__((ext_vector_type(4)));

__device__ __forceinline__ unsigned int encf(float f) {
  unsigned int u = __float_as_uint(f);
  return (u & 0x80000000u) ? ~u : (u | 0x80000000u);
}
__device__ __forceinline__ float decf(unsigned int e) {
  return (e & 0x80000000u) ? __uint_as_float(e & 0x7fffffffu) : __uint_as_float(~e);
}

// ================= CSR build: two-level locality-aware counting sort =================
__global__ void bucket_count(const int* __restrict__ ei, int* __restrict__ bucketTotal) {
  __shared__ int cnt[NBUCK];
  const int t = threadIdx.x;  // 256
  cnt[t] = 0;
  __syncthreads();
  long start = (long)blockIdx.x * CHUNK;
  long end = min((long)NE, start + CHUNK);
  for (long e = start + t; e < end; e += 256)
    atomicAdd(&cnt[ei[NE + e] >> BSHIFT], 1);
  __syncthreads();
  if (cnt[t]) atomicAdd(&bucketTotal[t], cnt[t]);
}

__global__ void bucket_scan(const int* __restrict__ bucketTotal, int* __restrict__ bucketBase,
                            int* __restrict__ cursor) {
  __shared__ int part[NBUCK];
  const int t = threadIdx.x;  // 256
  int v = bucketTotal[t];
  part[t] = v;
  __syncthreads();
  for (int off = 1; off < NBUCK; off <<= 1) {
    int u = (t >= off) ? part[t - off] : 0;
    __syncthreads();
    part[t] += u;
    __syncthreads();
  }
  int base = part[t] - v;
  bucketBase[t] = base;
  cursor[t] = base;
  if (t == NBUCK - 1) bucketBase[NBUCK] = part[t];
}

__global__ void bucket_scatter(const int* __restrict__ ei, int* __restrict__ cursor,
                               unsigned int* __restrict__ binned) {
  __shared__ int cnt[NBUCK];
  __shared__ int runbase[NBUCK];
  const int t = threadIdx.x;  // 256
  cnt[t] = 0;
  __syncthreads();
  long start = (long)blockIdx.x * CHUNK;
  long end = min((long)NE, start + CHUNK);
  for (long e = start + t; e < end; e += 256)
    atomicAdd(&cnt[ei[NE + e] >> BSHIFT], 1);
  __syncthreads();
  int c = cnt[t];
  runbase[t] = c ? atomicAdd(&cursor[t], c) : 0;
  cnt[t] = 0;  // reuse as local run cursor
  __syncthreads();
  for (long e = start + t; e < end; e += 256) {
    int d = ei[NE + e], s = ei[e];
    int b = d >> BSHIFT;
    int pos = runbase[b] + atomicAdd(&cnt[b], 1);
    binned[pos] = ((unsigned int)s << BSHIFT) | (unsigned int)(d & (BSIZE - 1));
  }
}

__global__ void bucket_csr(const unsigned int* __restrict__ binned,
                           const int* __restrict__ bucketBase,
                           int* __restrict__ rowptr, int* __restrict__ col) {
  __shared__ int cnt[BSIZE];
  __shared__ int excl[BSIZE];
  __shared__ int cur[BSIZE];
  __shared__ int part[256];
  const int b = blockIdx.x;
  const int t = threadIdx.x;  // 256
  const int lo = bucketBase[b], hi = bucketBase[b + 1];
  cnt[t] = 0; cnt[t + 256] = 0;
  __syncthreads();
  for (int i = lo + t; i < hi; i += 256)
    atomicAdd(&cnt[binned[i] & (BSIZE - 1)], 1);
  __syncthreads();
  int a0 = cnt[2 * t], a1 = cnt[2 * t + 1];
  int s = a0 + a1;
  part[t] = s;
  __syncthreads();
  for (int off = 1; off < 256; off <<= 1) {
    int u = (t >= off) ? part[t - off] : 0;
    __syncthreads();
    part[t] += u;
    __syncthreads();
  }
  int ebase = part[t] - s;
  excl[2 * t] = ebase;
  excl[2 * t + 1] = ebase + a0;
  __syncthreads();
  const int node0 = b * BSIZE;
  for (int i = t; i < BSIZE; i += 256) {
    int node = node0 + i;
    if (node < NN) rowptr[node] = lo + excl[i] + cnt[i];  // inclusive end
    cur[i] = lo + excl[i];
  }
  __syncthreads();
  for (int i = lo + t; i < hi; i += 256) {
    unsigned int v = binned[i];
    int pos = atomicAdd(&cur[v & (BSIZE - 1)], 1);
    col[pos] = (int)(v >> BSHIFT);
  }
}

// ---------------- x fp32 -> fp16, once ----------------
__global__ void f32to16_kernel(const float* __restrict__ in, _Float16* __restrict__ out) {
  long i = (long)(blockIdx.x * 256 + threadIdx.x) * 8;
  if (i >= NH) return;
  float4 a = *reinterpret_cast<const float4*>(in + i);
  float4 b = *reinterpret_cast<const float4*>(in + i + 4);
  f16x8 v;
  v[0] = (_Float16)a.x; v[1] = (_Float16)a.y; v[2] = (_Float16)a.z; v[3] = (_Float16)a.w;
  v[4] = (_Float16)b.x; v[5] = (_Float16)b.y; v[6] = (_Float16)b.z; v[7] = (_Float16)b.w;
  *reinterpret_cast<f16x8*>(out + i) = v;
}

// ---------------- weight packing: fp32 W[128][128] -> fp16 MFMA B-fragments ----------------
__global__ void pack_w_kernel(const float* __restrict__ gW1, const float* __restrict__ gW2,
                              _Float16* __restrict__ Wp) {
  int tid = blockIdx.x * blockDim.x + threadIdx.x;  // 3*2*8*4*64 = 12288
  if (tid >= 12288) return;
  int lane = tid & 63;
  int s = (tid >> 6) & 3;
  int t = (tid >> 8) & 7;
  int which = (tid >> 11) & 1;
  int layer = tid >> 12;
  const float* W = (which ? gW2 : gW1) + (long)layer * 128 * 128;
  _Float16* dst = Wp + (long)tid * 8;
  int kbase = s * 32 + ((lane >> 4) << 3);
  int n = t * 16 + (lane & 15);
#pragma unroll
  for (int j = 0; j < 8; ++j) dst[j] = (_Float16)W[(kbase + j) * 128 + n];
}

// ---------------- gather: z[n] = f(hin[n]) + sum_j f(hin[col[j]]) ----------------
template <bool BN, bool RELU>
__global__ void gather_kernel(const _Float16* __restrict__ hin, const int* __restrict__ rowptr,
                              const int* __restrict__ col, const float* __restrict__ accum,
                              const float* __restrict__ gamma, const float* __restrict__ beta,
                              _Float16* __restrict__ z) {
  const int node = (blockIdx.x * blockDim.x + threadIdx.x) >> 6;
  if (node >= NN) return;
  const int c2 = (threadIdx.x & 63) * 2;
  float scx = 1.f, scy = 1.f, shx = 0.f, shy = 0.f;
  if (BN) {
    const float n = (float)NN;
    float mu0 = accum[c2] / n, mu1 = accum[c2 + 1] / n;
    float v0 = accum[128 + c2] / n - mu0 * mu0;
    float v1 = accum[128 + c2 + 1] / n - mu1 * mu1;
    scx = rsqrtf(v0 + 1e-5f) * gamma[c2];
    scy = rsqrtf(v1 + 1e-5f) * gamma[c2 + 1];
    shx = beta[c2] - mu0 * scx;
    shy = beta[c2 + 1] - mu1 * scy;
  }
  auto ldh = [&](int n) -> float2 {
    f16x2 h = *reinterpret_cast<const f16x2*>(hin + (long)n * HD + c2);
    float2 v = make_float2((float)h[0], (float)h[1]);
    if (BN) {
      v.x = fmaf(v.x, scx, shx);
      v.y = fmaf(v.y, scy, shy);
      if (RELU) { v.x = fmaxf(v.x, 0.f); v.y = fmaxf(v.y, 0.f); }
    }
    return v;
  };
  const int lo = (node == 0) ? 0 : rowptr[node - 1];
  const int hi = rowptr[node];
  float2 acc = ldh(node);
  int j = lo;
  for (; j + 4 <= hi; j += 4) {
    int s0 = col[j], s1 = col[j + 1], s2 = col[j + 2], s3 = col[j + 3];
    float2 v0 = ldh(s0), v1 = ldh(s1), v2 = ldh(s2), v3 = ldh(s3);
    acc.x += (v0.x + v1.x) + (v2.x + v3.x);
    acc.y += (v0.y + v1.y) + (v2.y + v3.y);
  }
  if (j < hi) {
    int last = hi - 1;
    int s0 = col[j];
    int s1 = col[min(j + 1, last)];
    int s2 = col[min(j + 2, last)];
    int s3 = col[min(j + 3, last)];
    float m1 = (j + 1 < hi) ? 1.f : 0.f;
    float m2 = (j + 2 < hi) ? 1.f : 0.f;
    float m3 = (j + 3 < hi) ? 1.f : 0.f;
    float2 v0 = ldh(s0), v1 = ldh(s1), v2 = ldh(s2), v3 = ldh(s3);
    acc.x += v0.x + m1 * v1.x + m2 * v2.x + m3 * v3.x;
    acc.y += v0.y + m1 * v1.y + m2 * v2.y + m3 * v3.y;
  }
  f16x2 o;
  o[0] = (_Float16)acc.x;
  o[1] = (_Float16)acc.y;
  *reinterpret_cast<f16x2*>(z + (long)node * HD + c2) = o;
}

// ---------------- fused GIN layer: z2 = (ReLU(z@W1+b1))@W2 + b2, BN stats fused ----------------
__global__ void __launch_bounds__(256)
fused_layer(const _Float16* __restrict__ Z, const _Float16* __restrict__ Wp,
            const float* __restrict__ b1, const float* __restrict__ b2,
            _Float16* __restrict__ Z2, float* __restrict__ accum) {
  __shared__ _Float16 Abuf[64 * 136];
  __shared__ _Float16 Hbuf[64 * 136];
  __shared__ float red[256];
  const int t = threadIdx.x;
  const int row0 = blockIdx.x * 64;
  const int lane = t & 63;
  const int w = t >> 6;
  const int l15 = lane & 15;
  const int kgrp = lane >> 4;

  for (int idx = t; idx < 64 * 16; idx += 256) {
    int r = idx >> 4;
    int c8 = (idx & 15) * 8;
    int row = row0 + r;
    f16x8 v = {};
    if (row < NN) v = *reinterpret_cast<const f16x8*>(Z + (long)row * HD + c8);
    *reinterpret_cast<f16x8*>(&Abuf[r * 136 + c8]) = v;
  }
  red[t] = 0.f;
  __syncthreads();

  f32x4 acc[8];
  // ---- GEMM1: hidden = ReLU(A @ W1 + b1) ----
  {
    f16x8 af[4];
#pragma unroll
    for (int s = 0; s < 4; ++s)
      af[s] = *reinterpret_cast<const f16x8*>(&Abuf[(w * 16 + l15) * 136 + s * 32 + kgrp * 8]);
    const _Float16* W1p = Wp;
#pragma unroll
    for (int tt = 0; tt < 8; ++tt) {
      float bb = b1[tt * 16 + l15];
      acc[tt] = (f32x4){bb, bb, bb, bb};
#pragma unroll
      for (int s = 0; s < 4; ++s) {
        f16x8 bf = *reinterpret_cast<const f16x8*>(W1p + ((tt * 4 + s) * 64 + lane) * 8);
        acc[tt] = __builtin_amdgcn_mfma_f32_16x16x32_f16(af[s], bf, acc[tt], 0, 0, 0);
      }
    }
  }
#pragma unroll
  for (int tt = 0; tt < 8; ++tt) {
#pragma unroll
    for (int j = 0; j < 4; ++j) {
      float v = fmaxf(acc[tt][j], 0.f);
      Hbuf[(w * 16 + kgrp * 4 + j) * 136 + tt * 16 + l15] = (_Float16)v;
    }
  }
  // ---- GEMM2: z2 = hidden @ W2 + b2 ----
  {
    f16x8 af[4];
#pragma unroll
    for (int s = 0; s < 4; ++s)
      af[s] = *reinterpret_cast<const f16x8*>(&Hbuf[(w * 16 + l15) * 136 + s * 32 + kgrp * 8]);
    const _Float16* W2p = Wp + 16384;
#pragma unroll
    for (int tt = 0; tt < 8; ++tt) {
      float bb = b2[tt * 16 + l15];
      acc[tt] = (f32x4){bb, bb, bb, bb};
#pragma unroll
      for (int s = 0; s < 4; ++s) {
        f16x8 bf = *reinterpret_cast<const f16x8*>(W2p + ((tt * 4 + s) * 64 + lane) * 8);
        acc[tt] = __builtin_amdgcn_mfma_f32_16x16x32_f16(af[s], bf, acc[tt], 0, 0, 0);
      }
    }
  }
#pragma unroll
  for (int tt = 0; tt < 8; ++tt) {
    int c = tt * 16 + l15;
    float s = 0.f, q = 0.f;
#pragma unroll
    for (int j = 0; j < 4; ++j) {
      int r = row0 + w * 16 + kgrp * 4 + j;
      if (r < NN) {
        float v = acc[tt][j];
        Z2[(long)r * HD + c] = (_Float16)v;
        s += v; q += v * v;
      }
    }
    atomicAdd(&red[c], s);
    atomicAdd(&red[128 + c], q);
  }
  __syncthreads();
  atomicAdd(&accum[t], red[t]);
}

// ---------------- 3-phase parallel pooling ----------------
__global__ void pool_init(float* __restrict__ ssum, unsigned int* __restrict__ smaxU) {
  int i = blockIdx.x * 256 + threadIdx.x;  // 32768
  ssum[i] = 0.f;
  smaxU[i] = 0x007FFFFFu;  // enc(-inf)
}

// block owns POOL_ROWS contiguous rows; batch sorted -> few segment flushes per block
__global__ void pool_partial(const _Float16* __restrict__ z2, const float* __restrict__ accum,
                             const float* __restrict__ gamma, const float* __restrict__ beta,
                             const int* __restrict__ batch,
                             float* __restrict__ ssum, unsigned int* __restrict__ smaxU) {
  const int c = threadIdx.x;  // 128
  const int row0 = blockIdx.x * POOL_ROWS;
  const int rowEnd = min(row0 + POOL_ROWS, NN);
  const float n = (float)NN;
  float mu = accum[c] / n;
  float var = accum[128 + c] / n - mu * mu;
  const float sc = rsqrtf(var + 1e-5f) * gamma[c];
  const float sh = beta[c] - mu * sc;

  int curb = batch[row0];
  float s = 0.f, m = -INFINITY;
  for (int row = row0; row < rowEnd; ++row) {
    int b = batch[row];
    if (b != curb) {
      atomicAdd(&ssum[curb * HD + c], s);
      atomicMax(&smaxU[curb * HD + c], encf(m));
      s = 0.f; m = -INFINITY; curb = b;
    }
    float v = fmaf((float)z2[(long)row * HD + c], sc, sh);
    s += v;
    m = fmaxf(m, v);
  }
  atomicAdd(&ssum[curb * HD + c], s);
  atomicMax(&smaxU[curb * HD + c], encf(m));
}

__global__ void pool_final(const int* __restrict__ batch, float* __restrict__ ssum,
                           unsigned int* __restrict__ smaxU, float* __restrict__ smean,
                           float* __restrict__ smax) {
  const int b = blockIdx.x;   // 256
  const int c = threadIdx.x;  // 128
  int lo = 0, hi = NN;
  while (lo < hi) { int mid = (lo + hi) >> 1; if (batch[mid] < b) lo = mid + 1; else hi = mid; }
  const int start = lo;
  hi = NN;
  while (lo < hi) { int mid = (lo + hi) >> 1; if (batch[mid] < b + 1) lo = mid + 1; else hi = mid; }
  const int cnt = lo - start;
  float s = ssum[b * HD + c];
  smean[b * HD + c] = s / fmaxf((float)cnt, 1.f);
  smax[b * HD + c] = (cnt > 0) ? decf(smaxU[b * HD + c]) : 0.f;
}

// ---------------- order encoder + score head ----------------
__global__ void head_kernel(const float* __restrict__ orders,
                            const float* __restrict__ oW1, const float* __restrict__ ob1,
                            const float* __restrict__ oW2, const float* __restrict__ ob2,
                            const float* __restrict__ sW1, const float* __restrict__ sb1,
                            const float* __restrict__ sW2, const float* __restrict__ sb2,
                            const float* __restrict__ sW3, const float* __restrict__ sb3,
                            const float* __restrict__ smean, const float* __restrict__ smax,
                            const float* __restrict__ ssum, float* __restrict__ out) {
  __shared__ float t1[128];
  __shared__ float comb[512];
  __shared__ float s1[128];
  __shared__ float s2[64];
  const int bo = blockIdx.x;
  const int b = bo >> 5;
  const int tid = threadIdx.x;  // 128

  {
    float acc = ob1[tid];
    const float* orow = orders + (long)bo * 32;
    for (int k = 0; k < 32; ++k) acc += orow[k] * oW1[k * 128 + tid];
    t1[tid] = fmaxf(acc, 0.0f);
  }
  comb[tid]       = smean[b * HD + tid];
  comb[128 + tid] = smax[b * HD + tid];
  comb[256 + tid] = ssum[b * HD + tid];
  __syncthreads();
  {
    float acc = ob2[tid];
    for (int k = 0; k < 128; ++k) acc += t1[k] * oW2[k * 128 + tid];
    comb[384 + tid] = acc;
  }
  __syncthreads();
  {
    float acc = sb1[tid];
    for (int k = 0; k < 512; ++k) acc += comb[k] * sW1[k * 128 + tid];
    s1[tid] = fmaxf(acc, 0.0f);
  }
  __syncthreads();
  if (tid < 64) {
    float acc = sb2[tid];
    for (int k = 0; k < 128; ++k) acc += s1[k] * sW2[k * 64 + tid];
    s2[tid] = fmaxf(acc, 0.0f);
  }
  __syncthreads();
  if (tid == 0) {
    float acc = sb3[0];
    for (int k = 0; k < 64; ++k) acc += s2[k] * sW3[k];
    out[bo] = acc;
  }
}

extern "C" void kernel_launch(void* const* d_in, const int* in_sizes, int n_in,
                              void* d_out, int out_size, void* d_ws, size_t ws_size,
                              hipStream_t stream) {
  const float* x      = (const float*)d_in[0];
  const int*   ei     = (const int*)d_in[1];
  const float* orders = (const float*)d_in[2];
  const int*   batch  = (const int*)d_in[3];
  const float* gW1    = (const float*)d_in[4];
  const float* gb1    = (const float*)d_in[5];
  const float* gW2    = (const float*)d_in[6];
  const float* gb2    = (const float*)d_in[7];
  const float* gamma  = (const float*)d_in[8];
  const float* beta   = (const float*)d_in[9];
  const float* oW1    = (const float*)d_in[10];
  const float* ob1    = (const float*)d_in[11];
  const float* oW2    = (const float*)d_in[12];
  const float* ob2    = (const float*)d_in[13];
  const float* sW1    = (const float*)d_in[14];
  const float* sb1    = (const float*)d_in[15];
  const float* sW2    = (const float*)d_in[16];
  const float* sb2    = (const float*)d_in[17];
  const float* sW3    = (const float*)d_in[18];
  const float* sb3    = (const float*)d_in[19];
  float* out = (float*)d_out;

  char* ws = (char*)d_ws;
  _Float16* xh    = (_Float16*)ws;                // x fp16        [NN,128]
  _Float16* bufAh = xh + NH;                      // z fp16        [NN,128]
  _Float16* bufCh = bufAh + NH;                   // z2 fp16       [NN,128]
  float* accum = (float*)(bufCh + NH);            // 256
  float* ssum  = accum + 256;                     // 256*128
  float* smean = ssum + NB * HD;                  // 256*128
  float* smax  = smean + NB * HD;                 // 256*128
  unsigned int* smaxU = (unsigned int*)(smax + NB * HD);  // 256*128
  int* rowptr = (int*)(smaxU + NB * HD);          // NN
  int* col    = rowptr + NN;                      // NE
  unsigned int* binned = (unsigned int*)(col + NE);  // NE
  int* bucketTotal = (int*)(binned + NE);         // 256
  int* bucketBase  = bucketTotal + NBUCK;         // 257
  int* cursor      = bucketBase + NBUCK + 1;      // 256
  _Float16* Wp = (_Float16*)(cursor + NBUCK);     // 3*2*16384 fp16

  // ---- CSR build (by dst): two-level locality-aware counting sort ----
  hipMemsetAsync(bucketTotal, 0, NBUCK * sizeof(int), stream);
  bucket_count<<<NCHUNK, 256, 0, stream>>>(ei, bucketTotal);
  bucket_scan<<<1, NBUCK, 0, stream>>>(bucketTotal, bucketBase, cursor);
  bucket_scatter<<<NCHUNK, 256, 0, stream>>>(ei, cursor, binned);
  bucket_csr<<<NBUCK, 256, 0, stream>>>(binned, bucketBase, rowptr, col);

  // ---- pack weights + convert x, once ----
  pack_w_kernel<<<48, 256, 0, stream>>>(gW1, gW2, Wp);
  f32to16_kernel<<<(int)(NH / 8 + 255) / 256, 256, 0, stream>>>(x, xh);

  const int GATHER_GRID = NN / 4;
  const int LAYER_GRID = (NN + 63) / 64;
  for (int l = 0; l < 3; ++l) {
    if (l == 0)
      gather_kernel<false, false><<<GATHER_GRID, 256, 0, stream>>>(
          xh, rowptr, col, accum, gamma, beta, bufAh);
    else
      gather_kernel<true, true><<<GATHER_GRID, 256, 0, stream>>>(
          bufCh, rowptr, col, accum, gamma + (l - 1) * 128, beta + (l - 1) * 128, bufAh);
    hipMemsetAsync(accum, 0, 256 * sizeof(float), stream);
    fused_layer<<<LAYER_GRID, 256, 0, stream>>>(
        bufAh, Wp + (long)l * 32768, gb1 + l * 128, gb2 + l * 128, bufCh, accum);
  }

  // ---- 3-phase pooling (BN of last layer fused into partial) ----
  pool_init<<<128, 256, 0, stream>>>(ssum, smaxU);
  pool_partial<<<POOL_GRID, 128, 0, stream>>>(bufCh, accum, gamma + 2 * 128, beta + 2 * 128,
                                              batch, ssum, smaxU);
  pool_final<<<NB, 128, 0, stream>>>(batch, ssum, smaxU, smean, smax);

  head_kernel<<<NB * NO, 128, 0, stream>>>(orders, oW1, ob1, oW2, ob2,
                                           sW1, sb1, sW2, sb2, sW3, sb3,
                                           smean, smax, ssum, out);
}

// Round 9
// 596.634 us; speedup vs baseline: 16.1688x; 1.0818x over previous
//
#include <hip/hip_runtime.h>

static constexpr int NN = 100000;   // nodes
static constexpr int NE = 1600000;  // edges
static constexpr int NB = 256;     // graphs
static constexpr int NO = 32;      // orders per graph
static constexpr int HD = 128;     // hidden dim
static constexpr long NH = (long)NN * HD;

static constexpr int BSHIFT = 9;                 // bucket = dst >> 9
static constexpr int BSIZE = 1 << BSHIFT;        // 512 nodes per bucket
static constexpr int NBUCK = 256;
static constexpr int CHUNK = 16384;
static constexpr int NCHUNK = (NE + CHUNK - 1) / CHUNK;  // 98
static constexpr int POOL_ROWS = 64;
static constexpr int POOL_GRID = (NN + POOL_ROWS - 1) / POOL_ROWS;  // 1563

typedef _Float16 f16x8 __attribute__((ext_vector_type(8)));
typedef _Float16 f16x4 __attribute__((ext_vector_type(4)));
typedef _Float16 f16x2 __attribute__((ext_vector_type(2)));
typedef float f32x4 __attribute__((ext_vector_type(4)));

__device__ __forceinline__ unsigned int encf(float f) {
  unsigned int u = __float_as_uint(f);
  return (u & 0x80000000u) ? ~u : (u | 0x80000000u);
}
__device__ __forceinline__ float decf(unsigned int e) {
  return (e & 0x80000000u) ? __uint_as_float(e & 0x7fffffffu) : __uint_as_float(~e);
}

// ================= CSR build: two-level locality-aware counting sort =================
__global__ void bucket_count(const int* __restrict__ ei, int* __restrict__ bucketTotal) {
  __shared__ int cnt[NBUCK];
  const int t = threadIdx.x;  // 256
  cnt[t] = 0;
  __syncthreads();
  long start = (long)blockIdx.x * CHUNK;
  long end = min((long)NE, start + CHUNK);
  for (long e = start + t; e < end; e += 256)
    atomicAdd(&cnt[ei[NE + e] >> BSHIFT], 1);
  __syncthreads();
  if (cnt[t]) atomicAdd(&bucketTotal[t], cnt[t]);
}

__global__ void bucket_scan(const int* __restrict__ bucketTotal, int* __restrict__ bucketBase,
                            int* __restrict__ cursor) {
  __shared__ int part[NBUCK];
  const int t = threadIdx.x;  // 256
  int v = bucketTotal[t];
  part[t] = v;
  __syncthreads();
  for (int off = 1; off < NBUCK; off <<= 1) {
    int u = (t >= off) ? part[t - off] : 0;
    __syncthreads();
    part[t] += u;
    __syncthreads();
  }
  int base = part[t] - v;
  bucketBase[t] = base;
  cursor[t] = base;
  if (t == NBUCK - 1) bucketBase[NBUCK] = part[t];
}

__global__ void bucket_scatter(const int* __restrict__ ei, int* __restrict__ cursor,
                               unsigned int* __restrict__ binned) {
  __shared__ int cnt[NBUCK];
  __shared__ int runbase[NBUCK];
  const int t = threadIdx.x;  // 256
  cnt[t] = 0;
  __syncthreads();
  long start = (long)blockIdx.x * CHUNK;
  long end = min((long)NE, start + CHUNK);
  for (long e = start + t; e < end; e += 256)
    atomicAdd(&cnt[ei[NE + e] >> BSHIFT], 1);
  __syncthreads();
  int c = cnt[t];
  runbase[t] = c ? atomicAdd(&cursor[t], c) : 0;
  cnt[t] = 0;  // reuse as local run cursor
  __syncthreads();
  for (long e = start + t; e < end; e += 256) {
    int d = ei[NE + e], s = ei[e];
    int b = d >> BSHIFT;
    int pos = runbase[b] + atomicAdd(&cnt[b], 1);
    binned[pos] = ((unsigned int)s << BSHIFT) | (unsigned int)(d & (BSIZE - 1));
  }
}

__global__ void bucket_csr(const unsigned int* __restrict__ binned,
                           const int* __restrict__ bucketBase,
                           int* __restrict__ rowptr, int* __restrict__ col) {
  __shared__ int cnt[BSIZE];
  __shared__ int excl[BSIZE];
  __shared__ int cur[BSIZE];
  __shared__ int part[256];
  const int b = blockIdx.x;
  const int t = threadIdx.x;  // 256
  const int lo = bucketBase[b], hi = bucketBase[b + 1];
  cnt[t] = 0; cnt[t + 256] = 0;
  __syncthreads();
  for (int i = lo + t; i < hi; i += 256)
    atomicAdd(&cnt[binned[i] & (BSIZE - 1)], 1);
  __syncthreads();
  int a0 = cnt[2 * t], a1 = cnt[2 * t + 1];
  int s = a0 + a1;
  part[t] = s;
  __syncthreads();
  for (int off = 1; off < 256; off <<= 1) {
    int u = (t >= off) ? part[t - off] : 0;
    __syncthreads();
    part[t] += u;
    __syncthreads();
  }
  int ebase = part[t] - s;
  excl[2 * t] = ebase;
  excl[2 * t + 1] = ebase + a0;
  __syncthreads();
  const int node0 = b * BSIZE;
  for (int i = t; i < BSIZE; i += 256) {
    int node = node0 + i;
    if (node < NN) rowptr[node] = lo + excl[i] + cnt[i];  // inclusive end
    cur[i] = lo + excl[i];
  }
  __syncthreads();
  for (int i = lo + t; i < hi; i += 256) {
    unsigned int v = binned[i];
    int pos = atomicAdd(&cur[v & (BSIZE - 1)], 1);
    col[pos] = (int)(v >> BSHIFT);
  }
}

// ---------------- x fp32 -> fp16, once ----------------
__global__ void f32to16_kernel(const float* __restrict__ in, _Float16* __restrict__ out) {
  long i = (long)(blockIdx.x * 256 + threadIdx.x) * 8;
  if (i >= NH) return;
  float4 a = *reinterpret_cast<const float4*>(in + i);
  float4 b = *reinterpret_cast<const float4*>(in + i + 4);
  f16x8 v;
  v[0] = (_Float16)a.x; v[1] = (_Float16)a.y; v[2] = (_Float16)a.z; v[3] = (_Float16)a.w;
  v[4] = (_Float16)b.x; v[5] = (_Float16)b.y; v[6] = (_Float16)b.z; v[7] = (_Float16)b.w;
  *reinterpret_cast<f16x8*>(out + i) = v;
}

// ---------------- weight packing: fp32 W[128][128] -> fp16 MFMA B-fragments (GIN) ----------------
__global__ void pack_w_kernel(const float* __restrict__ gW1, const float* __restrict__ gW2,
                              _Float16* __restrict__ Wp) {
  int tid = blockIdx.x * blockDim.x + threadIdx.x;  // 3*2*8*4*64 = 12288
  if (tid >= 12288) return;
  int lane = tid & 63;
  int s = (tid >> 6) & 3;
  int t = (tid >> 8) & 7;
  int which = (tid >> 11) & 1;
  int layer = tid >> 12;
  const float* W = (which ? gW2 : gW1) + (long)layer * 128 * 128;
  _Float16* dst = Wp + (long)tid * 8;
  int kbase = s * 32 + ((lane >> 4) << 3);
  int n = t * 16 + (lane & 15);
#pragma unroll
  for (int j = 0; j < 8; ++j) dst[j] = (_Float16)W[(kbase + j) * 128 + n];
}

// ---------------- head weight packing: oW1,oW2,sW1[384:],sW2 -> fp16 B-fragments ----------------
// frag id = ((tt*NS + s)*64 + lane)*8; value = W[rowOff + s*32+(lane>>4)*8+j][tt*16+(lane&15)]
// layout in dst (halves): oW1p@0 (4096), oW2p@4096 (16384), sW1bp@20480 (16384), sW2p@36864 (8192)
__global__ void pack_head_kernel(const float* __restrict__ oW1, const float* __restrict__ oW2,
                                 const float* __restrict__ sW1, const float* __restrict__ sW2,
                                 _Float16* __restrict__ dst) {
  int tid = blockIdx.x * blockDim.x + threadIdx.x;  // 5632 total
  if (tid >= 5632) return;
  const float* W; int K, N, rowOff;
  int base = tid;
  if (tid < 512)       { W = oW1; K = 32;  N = 128; rowOff = 0;   }
  else if (tid < 2560) { W = oW2; K = 128; N = 128; rowOff = 0;   base = tid - 512; }
  else if (tid < 4608) { W = sW1; K = 128; N = 128; rowOff = 384; base = tid - 2560; }
  else                 { W = sW2; K = 128; N = 64;  rowOff = 0;   base = tid - 4608; }
  int lane = base & 63;
  int fs = base >> 6;
  int NS = K >> 5;
  int s = fs % NS;
  int tt = fs / NS;
  int k = s * 32 + ((lane >> 4) << 3);
  int n = tt * 16 + (lane & 15);
  _Float16* d = dst + (long)tid * 8;
#pragma unroll
  for (int j = 0; j < 8; ++j) d[j] = (_Float16)W[(long)(rowOff + k + j) * N + n];
}

// ---------------- gather: z[n] = f(hin[n]) + sum_j f(hin[col[j]]) ----------------
template <bool BN, bool RELU>
__global__ void gather_kernel(const _Float16* __restrict__ hin, const int* __restrict__ rowptr,
                              const int* __restrict__ col, const float* __restrict__ accum,
                              const float* __restrict__ gamma, const float* __restrict__ beta,
                              _Float16* __restrict__ z) {
  const int node = (blockIdx.x * blockDim.x + threadIdx.x) >> 6;
  if (node >= NN) return;
  const int c2 = (threadIdx.x & 63) * 2;
  float scx = 1.f, scy = 1.f, shx = 0.f, shy = 0.f;
  if (BN) {
    const float n = (float)NN;
    float mu0 = accum[c2] / n, mu1 = accum[c2 + 1] / n;
    float v0 = accum[128 + c2] / n - mu0 * mu0;
    float v1 = accum[128 + c2 + 1] / n - mu1 * mu1;
    scx = rsqrtf(v0 + 1e-5f) * gamma[c2];
    scy = rsqrtf(v1 + 1e-5f) * gamma[c2 + 1];
    shx = beta[c2] - mu0 * scx;
    shy = beta[c2 + 1] - mu1 * scy;
  }
  auto ldh = [&](int n) -> float2 {
    f16x2 h = *reinterpret_cast<const f16x2*>(hin + (long)n * HD + c2);
    float2 v = make_float2((float)h[0], (float)h[1]);
    if (BN) {
      v.x = fmaf(v.x, scx, shx);
      v.y = fmaf(v.y, scy, shy);
      if (RELU) { v.x = fmaxf(v.x, 0.f); v.y = fmaxf(v.y, 0.f); }
    }
    return v;
  };
  const int lo = (node == 0) ? 0 : rowptr[node - 1];
  const int hi = rowptr[node];
  float2 acc = ldh(node);
  int j = lo;
  for (; j + 4 <= hi; j += 4) {
    int s0 = col[j], s1 = col[j + 1], s2 = col[j + 2], s3 = col[j + 3];
    float2 v0 = ldh(s0), v1 = ldh(s1), v2 = ldh(s2), v3 = ldh(s3);
    acc.x += (v0.x + v1.x) + (v2.x + v3.x);
    acc.y += (v0.y + v1.y) + (v2.y + v3.y);
  }
  if (j < hi) {
    int last = hi - 1;
    int s0 = col[j];
    int s1 = col[min(j + 1, last)];
    int s2 = col[min(j + 2, last)];
    int s3 = col[min(j + 3, last)];
    float m1 = (j + 1 < hi) ? 1.f : 0.f;
    float m2 = (j + 2 < hi) ? 1.f : 0.f;
    float m3 = (j + 3 < hi) ? 1.f : 0.f;
    float2 v0 = ldh(s0), v1 = ldh(s1), v2 = ldh(s2), v3 = ldh(s3);
    acc.x += v0.x + m1 * v1.x + m2 * v2.x + m3 * v3.x;
    acc.y += v0.y + m1 * v1.y + m2 * v2.y + m3 * v3.y;
  }
  f16x2 o;
  o[0] = (_Float16)acc.x;
  o[1] = (_Float16)acc.y;
  *reinterpret_cast<f16x2*>(z + (long)node * HD + c2) = o;
}

// ---------------- fused GIN layer: z2 = (ReLU(z@W1+b1))@W2 + b2, BN stats fused ----------------
__global__ void __launch_bounds__(256)
fused_layer(const _Float16* __restrict__ Z, const _Float16* __restrict__ Wp,
            const float* __restrict__ b1, const float* __restrict__ b2,
            _Float16* __restrict__ Z2, float* __restrict__ accum) {
  __shared__ _Float16 Abuf[64 * 136];
  __shared__ _Float16 Hbuf[64 * 136];
  __shared__ float red[256];
  const int t = threadIdx.x;
  const int row0 = blockIdx.x * 64;
  const int lane = t & 63;
  const int w = t >> 6;
  const int l15 = lane & 15;
  const int kgrp = lane >> 4;

  for (int idx = t; idx < 64 * 16; idx += 256) {
    int r = idx >> 4;
    int c8 = (idx & 15) * 8;
    int row = row0 + r;
    f16x8 v = {};
    if (row < NN) v = *reinterpret_cast<const f16x8*>(Z + (long)row * HD + c8);
    *reinterpret_cast<f16x8*>(&Abuf[r * 136 + c8]) = v;
  }
  red[t] = 0.f;
  __syncthreads();

  f32x4 acc[8];
  // ---- GEMM1: hidden = ReLU(A @ W1 + b1) ----
  {
    f16x8 af[4];
#pragma unroll
    for (int s = 0; s < 4; ++s)
      af[s] = *reinterpret_cast<const f16x8*>(&Abuf[(w * 16 + l15) * 136 + s * 32 + kgrp * 8]);
    const _Float16* W1p = Wp;
#pragma unroll
    for (int tt = 0; tt < 8; ++tt) {
      float bb = b1[tt * 16 + l15];
      acc[tt] = (f32x4){bb, bb, bb, bb};
#pragma unroll
      for (int s = 0; s < 4; ++s) {
        f16x8 bf = *reinterpret_cast<const f16x8*>(W1p + ((tt * 4 + s) * 64 + lane) * 8);
        acc[tt] = __builtin_amdgcn_mfma_f32_16x16x32_f16(af[s], bf, acc[tt], 0, 0, 0);
      }
    }
  }
#pragma unroll
  for (int tt = 0; tt < 8; ++tt) {
#pragma unroll
    for (int j = 0; j < 4; ++j) {
      float v = fmaxf(acc[tt][j], 0.f);
      Hbuf[(w * 16 + kgrp * 4 + j) * 136 + tt * 16 + l15] = (_Float16)v;
    }
  }
  // ---- GEMM2: z2 = hidden @ W2 + b2 ----
  {
    f16x8 af[4];
#pragma unroll
    for (int s = 0; s < 4; ++s)
      af[s] = *reinterpret_cast<const f16x8*>(&Hbuf[(w * 16 + l15) * 136 + s * 32 + kgrp * 8]);
    const _Float16* W2p = Wp + 16384;
#pragma unroll
    for (int tt = 0; tt < 8; ++tt) {
      float bb = b2[tt * 16 + l15];
      acc[tt] = (f32x4){bb, bb, bb, bb};
#pragma unroll
      for (int s = 0; s < 4; ++s) {
        f16x8 bf = *reinterpret_cast<const f16x8*>(W2p + ((tt * 4 + s) * 64 + lane) * 8);
        acc[tt] = __builtin_amdgcn_mfma_f32_16x16x32_f16(af[s], bf, acc[tt], 0, 0, 0);
      }
    }
  }
#pragma unroll
  for (int tt = 0; tt < 8; ++tt) {
    int c = tt * 16 + l15;
    float s = 0.f, q = 0.f;
#pragma unroll
    for (int j = 0; j < 4; ++j) {
      int r = row0 + w * 16 + kgrp * 4 + j;
      if (r < NN) {
        float v = acc[tt][j];
        Z2[(long)r * HD + c] = (_Float16)v;
        s += v; q += v * v;
      }
    }
    atomicAdd(&red[c], s);
    atomicAdd(&red[128 + c], q);
  }
  __syncthreads();
  atomicAdd(&accum[t], red[t]);
}

// ---------------- 3-phase parallel pooling ----------------
__global__ void pool_init(float* __restrict__ ssum, unsigned int* __restrict__ smaxU) {
  int i = blockIdx.x * 256 + threadIdx.x;  // 32768
  ssum[i] = 0.f;
  smaxU[i] = 0x007FFFFFu;  // enc(-inf)
}

__global__ void pool_partial(const _Float16* __restrict__ z2, const float* __restrict__ accum,
                             const float* __restrict__ gamma, const float* __restrict__ beta,
                             const int* __restrict__ batch,
                             float* __restrict__ ssum, unsigned int* __restrict__ smaxU) {
  const int c = threadIdx.x;  // 128
  const int row0 = blockIdx.x * POOL_ROWS;
  const int rowEnd = min(row0 + POOL_ROWS, NN);
  const float n = (float)NN;
  float mu = accum[c] / n;
  float var = accum[128 + c] / n - mu * mu;
  const float sc = rsqrtf(var + 1e-5f) * gamma[c];
  const float sh = beta[c] - mu * sc;

  int curb = batch[row0];
  float s = 0.f, m = -INFINITY;
  for (int row = row0; row < rowEnd; ++row) {
    int b = batch[row];
    if (b != curb) {
      atomicAdd(&ssum[curb * HD + c], s);
      atomicMax(&smaxU[curb * HD + c], encf(m));
      s = 0.f; m = -INFINITY; curb = b;
    }
    float v = fmaf((float)z2[(long)row * HD + c], sc, sh);
    s += v;
    m = fmaxf(m, v);
  }
  atomicAdd(&ssum[curb * HD + c], s);
  atomicMax(&smaxU[curb * HD + c], encf(m));
}

__global__ void pool_final(const int* __restrict__ batch, float* __restrict__ ssum,
                           unsigned int* __restrict__ smaxU, float* __restrict__ smean,
                           float* __restrict__ smax) {
  const int b = blockIdx.x;   // 256
  const int c = threadIdx.x;  // 128
  int lo = 0, hi = NN;
  while (lo < hi) { int mid = (lo + hi) >> 1; if (batch[mid] < b) lo = mid + 1; else hi = mid; }
  const int start = lo;
  hi = NN;
  while (lo < hi) { int mid = (lo + hi) >> 1; if (batch[mid] < b + 1) lo = mid + 1; else hi = mid; }
  const int cnt = lo - start;
  float s = ssum[b * HD + c];
  smean[b * HD + c] = s / fmaxf((float)cnt, 1.f);
  smax[b * HD + c] = (cnt > 0) ? decf(smaxU[b * HD + c]) : 0.f;
}

// ---------------- gpart[b] = graph[b] @ sW1[0:384] + sb1 (fp32, per-graph, hoisted) ----------------
__global__ void gpart_kernel(const float* __restrict__ smean, const float* __restrict__ smax,
                             const float* __restrict__ ssum, const float* __restrict__ sW1,
                             const float* __restrict__ sb1, float* __restrict__ gpart) {
  const int b = blockIdx.x;   // 256
  const int j = threadIdx.x;  // 128
  float acc = sb1[j];
  for (int k = 0; k < 128; ++k) acc = fmaf(smean[b * HD + k], sW1[k * 128 + j], acc);
  for (int k = 0; k < 128; ++k) acc = fmaf(smax[b * HD + k], sW1[(128 + k) * 128 + j], acc);
  for (int k = 0; k < 128; ++k) acc = fmaf(ssum[b * HD + k], sW1[(256 + k) * 128 + j], acc);
  gpart[b * HD + j] = acc;
}

// ---------------- head MFMA: per-order chain, one block per graph (32 orders) ----------------
// 128 threads = 2 waves; wave w owns rows w*16..w*16+16 (order rows). fp16 MFMA 16x16x32.
__global__ void __launch_bounds__(128)
head_mfma(const float* __restrict__ orders, const _Float16* __restrict__ Wh,
          const float* __restrict__ ob1, const float* __restrict__ ob2,
          const float* __restrict__ gpart, const float* __restrict__ sb2,
          const float* __restrict__ sW3, const float* __restrict__ sb3,
          float* __restrict__ out) {
  __shared__ _Float16 B1[32 * 136];
  __shared__ _Float16 B2[32 * 136];
  const int t = threadIdx.x;
  const int g = blockIdx.x;        // graph; rows g*32..g*32+31
  const int row0 = g * 32;
  const int lane = t & 63;
  const int w = t >> 6;            // 2 waves
  const int l15 = lane & 15;
  const int kgrp = lane >> 4;
  const _Float16* oW1p  = Wh;
  const _Float16* oW2p  = Wh + 4096;
  const _Float16* sW1bp = Wh + 20480;
  const _Float16* sW2p  = Wh + 36864;

  // stage orders [32][32] fp32 -> fp16, row stride 136
  for (int idx = t; idx < 32 * 8; idx += 128) {
    int r = idx >> 3;
    int c4 = (idx & 7) * 4;
    float4 v = *reinterpret_cast<const float4*>(orders + (long)(row0 + r) * 32 + c4);
    f16x4 h;
    h[0] = (_Float16)v.x; h[1] = (_Float16)v.y; h[2] = (_Float16)v.z; h[3] = (_Float16)v.w;
    *reinterpret_cast<f16x4*>(&B1[r * 136 + c4]) = h;
  }
  __syncthreads();

  f32x4 acc[8];
  // ---- t1 = ReLU(orders @ oW1 + ob1), K=32, N=128 ----
  {
    f16x8 a0 = *reinterpret_cast<const f16x8*>(&B1[(w * 16 + l15) * 136 + kgrp * 8]);
#pragma unroll
    for (int tt = 0; tt < 8; ++tt) {
      float bb = ob1[tt * 16 + l15];
      acc[tt] = (f32x4){bb, bb, bb, bb};
      f16x8 bf = *reinterpret_cast<const f16x8*>(oW1p + (tt * 64 + lane) * 8);
      acc[tt] = __builtin_amdgcn_mfma_f32_16x16x32_f16(a0, bf, acc[tt], 0, 0, 0);
    }
#pragma unroll
    for (int tt = 0; tt < 8; ++tt)
#pragma unroll
      for (int j = 0; j < 4; ++j)
        B2[(w * 16 + kgrp * 4 + j) * 136 + tt * 16 + l15] = (_Float16)fmaxf(acc[tt][j], 0.f);
  }
  // ---- oe = t1 @ oW2 + ob2, K=128, N=128 ----
  {
    f16x8 af[4];
#pragma unroll
    for (int s = 0; s < 4; ++s)
      af[s] = *reinterpret_cast<const f16x8*>(&B2[(w * 16 + l15) * 136 + s * 32 + kgrp * 8]);
#pragma unroll
    for (int tt = 0; tt < 8; ++tt) {
      float bb = ob2[tt * 16 + l15];
      acc[tt] = (f32x4){bb, bb, bb, bb};
#pragma unroll
      for (int s = 0; s < 4; ++s) {
        f16x8 bf = *reinterpret_cast<const f16x8*>(oW2p + ((tt * 4 + s) * 64 + lane) * 8);
        acc[tt] = __builtin_amdgcn_mfma_f32_16x16x32_f16(af[s], bf, acc[tt], 0, 0, 0);
      }
    }
#pragma unroll
    for (int tt = 0; tt < 8; ++tt)
#pragma unroll
      for (int j = 0; j < 4; ++j)
        B1[(w * 16 + kgrp * 4 + j) * 136 + tt * 16 + l15] = (_Float16)acc[tt][j];
  }
  // ---- s1 = ReLU(oe @ sW1[384:] + gpart[g] (incl sb1)), K=128, N=128 ----
  {
    f16x8 af[4];
#pragma unroll
    for (int s = 0; s < 4; ++s)
      af[s] = *reinterpret_cast<const f16x8*>(&B1[(w * 16 + l15) * 136 + s * 32 + kgrp * 8]);
#pragma unroll
    for (int tt = 0; tt < 8; ++tt) {
      acc[tt] = (f32x4){0.f, 0.f, 0.f, 0.f};
#pragma unroll
      for (int s = 0; s < 4; ++s) {
        f16x8 bf = *reinterpret_cast<const f16x8*>(sW1bp + ((tt * 4 + s) * 64 + lane) * 8);
        acc[tt] = __builtin_amdgcn_mfma_f32_16x16x32_f16(af[s], bf, acc[tt], 0, 0, 0);
      }
    }
#pragma unroll
    for (int tt = 0; tt < 8; ++tt) {
      int c = tt * 16 + l15;
      float gp = gpart[g * HD + c];
#pragma unroll
      for (int j = 0; j < 4; ++j)
        B2[(w * 16 + kgrp * 4 + j) * 136 + c] = (_Float16)fmaxf(acc[tt][j] + gp, 0.f);
    }
  }
  // ---- s2 = ReLU(s1 @ sW2 + sb2), K=128, N=64; then out = s2 @ sW3 + sb3 ----
  {
    f16x8 af[4];
#pragma unroll
    for (int s = 0; s < 4; ++s)
      af[s] = *reinterpret_cast<const f16x8*>(&B2[(w * 16 + l15) * 136 + s * 32 + kgrp * 8]);
#pragma unroll
    for (int tt = 0; tt < 4; ++tt) {
      float bb = sb2[tt * 16 + l15];
      acc[tt] = (f32x4){bb, bb, bb, bb};
#pragma unroll
      for (int s = 0; s < 4; ++s) {
        f16x8 bf = *reinterpret_cast<const f16x8*>(sW2p + ((tt * 4 + s) * 64 + lane) * 8);
        acc[tt] = __builtin_amdgcn_mfma_f32_16x16x32_f16(af[s], bf, acc[tt], 0, 0, 0);
      }
    }
    // final dot: rsum[j] = sum_c ReLU(s2[row][c]) * sW3[c]; reduce over l15 lanes
    float rsum[4] = {0.f, 0.f, 0.f, 0.f};
#pragma unroll
    for (int tt = 0; tt < 4; ++tt) {
      float wv = sW3[tt * 16 + l15];
#pragma unroll
      for (int j = 0; j < 4; ++j)
        rsum[j] = fmaf(fmaxf(acc[tt][j], 0.f), wv, rsum[j]);
    }
#pragma unroll
    for (int j = 0; j < 4; ++j) {
      rsum[j] += __shfl_xor(rsum[j], 1);
      rsum[j] += __shfl_xor(rsum[j], 2);
      rsum[j] += __shfl_xor(rsum[j], 4);
      rsum[j] += __shfl_xor(rsum[j], 8);
    }
    if (l15 == 0) {
      float b3 = sb3[0];
#pragma unroll
      for (int j = 0; j < 4; ++j)
        out[row0 + w * 16 + kgrp * 4 + j] = rsum[j] + b3;
    }
  }
}

extern "C" void kernel_launch(void* const* d_in, const int* in_sizes, int n_in,
                              void* d_out, int out_size, void* d_ws, size_t ws_size,
                              hipStream_t stream) {
  const float* x      = (const float*)d_in[0];
  const int*   ei     = (const int*)d_in[1];
  const float* orders = (const float*)d_in[2];
  const int*   batch  = (const int*)d_in[3];
  const float* gW1    = (const float*)d_in[4];
  const float* gb1    = (const float*)d_in[5];
  const float* gW2    = (const float*)d_in[6];
  const float* gb2    = (const float*)d_in[7];
  const float* gamma  = (const float*)d_in[8];
  const float* beta   = (const float*)d_in[9];
  const float* oW1    = (const float*)d_in[10];
  const float* ob1    = (const float*)d_in[11];
  const float* oW2    = (const float*)d_in[12];
  const float* ob2    = (const float*)d_in[13];
  const float* sW1    = (const float*)d_in[14];
  const float* sb1    = (const float*)d_in[15];
  const float* sW2    = (const float*)d_in[16];
  const float* sb2    = (const float*)d_in[17];
  const float* sW3    = (const float*)d_in[18];
  const float* sb3    = (const float*)d_in[19];
  float* out = (float*)d_out;

  char* ws = (char*)d_ws;
  _Float16* xh    = (_Float16*)ws;                // x fp16        [NN,128]
  _Float16* bufAh = xh + NH;                      // z fp16        [NN,128]
  _Float16* bufCh = bufAh + NH;                   // z2 fp16       [NN,128]
  float* accum = (float*)(bufCh + NH);            // 256
  float* ssum  = accum + 256;                     // 256*128
  float* smean = ssum + NB * HD;                  // 256*128
  float* smax  = smean + NB * HD;                 // 256*128
  unsigned int* smaxU = (unsigned int*)(smax + NB * HD);  // 256*128
  float* gpart = (float*)(smaxU + NB * HD);       // 256*128
  int* rowptr = (int*)(gpart + NB * HD);          // NN
  int* col    = rowptr + NN;                      // NE
  unsigned int* binned = (unsigned int*)(col + NE);  // NE
  int* bucketTotal = (int*)(binned + NE);         // 256
  int* bucketBase  = bucketTotal + NBUCK;         // 257
  int* cursor      = bucketBase + NBUCK + 1;      // 256
  _Float16* Wp  = (_Float16*)(cursor + NBUCK);    // 3*2*16384 fp16 (GIN)
  _Float16* Wh  = Wp + 3 * 32768;                 // 45056 fp16 (head)

  // ---- CSR build (by dst): two-level locality-aware counting sort ----
  hipMemsetAsync(bucketTotal, 0, NBUCK * sizeof(int), stream);
  bucket_count<<<NCHUNK, 256, 0, stream>>>(ei, bucketTotal);
  bucket_scan<<<1, NBUCK, 0, stream>>>(bucketTotal, bucketBase, cursor);
  bucket_scatter<<<NCHUNK, 256, 0, stream>>>(ei, cursor, binned);
  bucket_csr<<<NBUCK, 256, 0, stream>>>(binned, bucketBase, rowptr, col);

  // ---- pack weights + convert x, once ----
  pack_w_kernel<<<48, 256, 0, stream>>>(gW1, gW2, Wp);
  pack_head_kernel<<<22, 256, 0, stream>>>(oW1, oW2, sW1, sW2, Wh);
  f32to16_kernel<<<(int)(NH / 8 + 255) / 256, 256, 0, stream>>>(x, xh);

  const int GATHER_GRID = NN / 4;
  const int LAYER_GRID = (NN + 63) / 64;
  for (int l = 0; l < 3; ++l) {
    if (l == 0)
      gather_kernel<false, false><<<GATHER_GRID, 256, 0, stream>>>(
          xh, rowptr, col, accum, gamma, beta, bufAh);
    else
      gather_kernel<true, true><<<GATHER_GRID, 256, 0, stream>>>(
          bufCh, rowptr, col, accum, gamma + (l - 1) * 128, beta + (l - 1) * 128, bufAh);
    hipMemsetAsync(accum, 0, 256 * sizeof(float), stream);
    fused_layer<<<LAYER_GRID, 256, 0, stream>>>(
        bufAh, Wp + (long)l * 32768, gb1 + l * 128, gb2 + l * 128, bufCh, accum);
  }

  // ---- 3-phase pooling (BN of last layer fused into partial) ----
  pool_init<<<128, 256, 0, stream>>>(ssum, smaxU);
  pool_partial<<<POOL_GRID, 128, 0, stream>>>(bufCh, accum, gamma + 2 * 128, beta + 2 * 128,
                                              batch, ssum, smaxU);
  pool_final<<<NB, 128, 0, stream>>>(batch, ssum, smaxU, smean, smax);

  // ---- head: hoisted graph part + per-order MFMA chain ----
  gpart_kernel<<<NB, 128, 0, stream>>>(smean, smax, ssum, sW1, sb1, gpart);
  head_mfma<<<NB, 128, 0, stream>>>(orders, Wh, ob1, ob2, gpart, sb2, sW3, sb3, out);
}